// Round 1
// baseline (18097.110 us; speedup 1.0000x reference)
//
#include <hip/hip_runtime.h>

// ---------------------------------------------------------------------------
// SFGCN forward on MI355X. fp32 everywhere (correctness-first baseline).
// Pipeline:
//   xw = x @ W1                      (gemm_128x128, W staged in LDS)
//   s  = spmm(adj, xw)               (atomic scatter-add, s pre-zeroed)
//   hw = relu(s + b1) @ W2           (gemm_relu_128x64, relu+bias fused on load)
//   embX = b2 ; embX += spmm(adj,hw) (bias as init, atomic scatter-add)
//   final fused attention/softmax/log_softmax epilogue
// ---------------------------------------------------------------------------

// C[n][128] = X[n][128] @ W[128][128]; W staged in 64KB LDS,
// X read via wave-uniform broadcast float4 loads (L1-served).
__global__ __launch_bounds__(256) void gemm_128x128(
    const float* __restrict__ X, const float* __restrict__ W,
    float* __restrict__ C, int nrows) {
  __shared__ __attribute__((aligned(16))) float ws[128 * 128];
  int tid = threadIdx.x;
  const float4* W4 = (const float4*)W;
  float4* ws4 = (float4*)ws;
#pragma unroll
  for (int i = 0; i < 16; ++i) ws4[i * 256 + tid] = W4[i * 256 + tid];
  __syncthreads();

  long row0 = (long)blockIdx.x * 32;
  int c0 = tid & 63;   // lane -> col pair (c0, c0+64)
  int wv = tid >> 6;   // wave id 0..3 -> 8-row group
  const float* xrow[8];
#pragma unroll
  for (int r = 0; r < 8; ++r) {
    long rr = row0 + wv * 8 + r;
    if (rr > (long)nrows - 1) rr = (long)nrows - 1;
    xrow[r] = X + rr * 128;
  }
  float acc0[8] = {}, acc1[8] = {};
#pragma unroll 4
  for (int k4 = 0; k4 < 32; ++k4) {
    float wa[4], wb[4];
#pragma unroll
    for (int j = 0; j < 4; ++j) {
      wa[j] = ws[(k4 * 4 + j) * 128 + c0];
      wb[j] = ws[(k4 * 4 + j) * 128 + c0 + 64];
    }
#pragma unroll
    for (int r = 0; r < 8; ++r) {
      float4 xv = *(const float4*)(xrow[r] + k4 * 4);
      acc0[r] += xv.x * wa[0] + xv.y * wa[1] + xv.z * wa[2] + xv.w * wa[3];
      acc1[r] += xv.x * wb[0] + xv.y * wb[1] + xv.z * wb[2] + xv.w * wb[3];
    }
  }
#pragma unroll
  for (int r = 0; r < 8; ++r) {
    long rr = row0 + wv * 8 + r;
    if (rr < nrows) {
      C[rr * 128 + c0] = acc0[r];
      C[rr * 128 + c0 + 64] = acc1[r];
    }
  }
}

// H[n][64] = relu(S[n][128] + b1) @ W2[128][64]; relu+bias fused into LDS stage.
__global__ __launch_bounds__(256) void gemm_relu_128x64(
    const float* __restrict__ S, const float* __restrict__ B1,
    const float* __restrict__ W2, float* __restrict__ H, int nrows) {
  __shared__ __attribute__((aligned(16))) float ws[128 * 64];
  __shared__ __attribute__((aligned(16))) float xs[32 * 128];
  int tid = threadIdx.x;
  const float4* W4 = (const float4*)W2;
  float4* ws4 = (float4*)ws;
#pragma unroll
  for (int i = 0; i < 8; ++i) ws4[i * 256 + tid] = W4[i * 256 + tid];

  long row0 = (long)blockIdx.x * 32;
  const float4* S4 = (const float4*)S;
  float4 bv = ((const float4*)B1)[tid & 31];
  float4* xs4 = (float4*)xs;
  long lim4 = (long)nrows * 32;
#pragma unroll
  for (int i = 0; i < 4; ++i) {
    long idx4 = row0 * 32 + i * 256 + tid;
    float4 sv = (idx4 < lim4) ? S4[idx4] : make_float4(0.f, 0.f, 0.f, 0.f);
    sv.x = fmaxf(sv.x + bv.x, 0.f);
    sv.y = fmaxf(sv.y + bv.y, 0.f);
    sv.z = fmaxf(sv.z + bv.z, 0.f);
    sv.w = fmaxf(sv.w + bv.w, 0.f);
    xs4[i * 256 + tid] = sv;
  }
  __syncthreads();

  int c = tid & 63;
  int wv = tid >> 6;
  const float* xrow = xs + wv * 8 * 128;
  float acc[8] = {};
#pragma unroll 4
  for (int k4 = 0; k4 < 32; ++k4) {
    float wk[4];
#pragma unroll
    for (int j = 0; j < 4; ++j) wk[j] = ws[(k4 * 4 + j) * 64 + c];
#pragma unroll
    for (int r = 0; r < 8; ++r) {
      float4 xv = *(const float4*)(xrow + r * 128 + k4 * 4);
      acc[r] += xv.x * wk[0] + xv.y * wk[1] + xv.z * wk[2] + xv.w * wk[3];
    }
  }
#pragma unroll
  for (int r = 0; r < 8; ++r) {
    long rr = row0 + wv * 8 + r;
    if (rr < nrows) H[rr * 64 + c] = acc[r];
  }
}

// out[row[e]] += val[e] * h[col[e]]  over F4*4 features; F4 threads per edge.
template <int F4>
__global__ __launch_bounds__(256) void spmm_atomic(
    const int* __restrict__ row, const int* __restrict__ col,
    const float* __restrict__ val, const float* __restrict__ h,
    float* __restrict__ out, int nedges) {
  int tid = threadIdx.x;
  int lane = tid & (F4 - 1);
  int e = blockIdx.x * (256 / F4) + (tid / F4);
  if (e >= nedges) return;
  int r = row[e];
  int c = col[e];
  float v = val[e];
  float4 hv = ((const float4*)h)[(long)c * F4 + lane];
  float* o = out + ((long)r * F4 + lane) * 4;
  unsafeAtomicAdd(o + 0, v * hv.x);
  unsafeAtomicAdd(o + 1, v * hv.y);
  unsafeAtomicAdd(o + 2, v * hv.z);
  unsafeAtomicAdd(o + 3, v * hv.w);
}

__global__ __launch_bounds__(256) void init_bias64(
    float* __restrict__ out, const float* __restrict__ b, long total) {
  long i = (long)blockIdx.x * 256 + threadIdx.x;
  if (i < total) out[i] = b[i & 63];
}

// Fused attention + softmax + emb + log_softmax epilogue. One thread per node.
__global__ __launch_bounds__(256) void final_fuse(
    const float* __restrict__ emb1, const float* __restrict__ emb2,
    const float* __restrict__ com1, const float* __restrict__ com2,
    const float* __restrict__ attw1, const float* __restrict__ attb1,
    const float* __restrict__ attw2, const float* __restrict__ mlpw,
    const float* __restrict__ mlpb, float* __restrict__ out_logp,
    float* __restrict__ out_beta, float* __restrict__ out_emb, int n) {
  __shared__ __attribute__((aligned(16))) float w1s[64 * 16];
  __shared__ __attribute__((aligned(16))) float mws[64 * 8];
  __shared__ float b1s[16];
  __shared__ float w2s[16];
  __shared__ float mbs[8];
  int tid = threadIdx.x;
  for (int i = tid; i < 1024; i += 256) w1s[i] = attw1[i];
  for (int i = tid; i < 512; i += 256) mws[i] = mlpw[i];
  if (tid < 16) {
    b1s[tid] = attb1[tid];
    w2s[tid] = attw2[tid];
  }
  if (tid < 8) mbs[tid] = mlpb[tid];
  __syncthreads();

  long i = (long)blockIdx.x * 256 + tid;
  if (i >= n) return;
  const float4* e1 = (const float4*)emb1 + i * 16;
  const float4* e2 = (const float4*)emb2 + i * 16;
  const float4* c1 = (const float4*)com1 + i * 16;
  const float4* c2 = (const float4*)com2 + i * 16;

  // pass 1: attention scores a_k = z_k @ att_w1  (k = 0,1,2)
  float a0[16] = {}, a1[16] = {}, a2[16] = {};
#pragma unroll
  for (int j4 = 0; j4 < 16; ++j4) {
    float4 z0 = e1[j4], z1 = e2[j4];
    float4 x1 = c1[j4], x2 = c2[j4];
    float z0c[4] = {z0.x, z0.y, z0.z, z0.w};
    float z1c[4] = {z1.x, z1.y, z1.z, z1.w};
    float z2c[4] = {0.5f * (x1.x + x2.x), 0.5f * (x1.y + x2.y),
                    0.5f * (x1.z + x2.z), 0.5f * (x1.w + x2.w)};
#pragma unroll
    for (int jj = 0; jj < 4; ++jj) {
      int j = j4 * 4 + jj;
      const float4* wrow = (const float4*)(w1s + j * 16);
#pragma unroll
      for (int m4 = 0; m4 < 4; ++m4) {
        float4 w = wrow[m4];
        a0[m4 * 4 + 0] += z0c[jj] * w.x;
        a0[m4 * 4 + 1] += z0c[jj] * w.y;
        a0[m4 * 4 + 2] += z0c[jj] * w.z;
        a0[m4 * 4 + 3] += z0c[jj] * w.w;
        a1[m4 * 4 + 0] += z1c[jj] * w.x;
        a1[m4 * 4 + 1] += z1c[jj] * w.y;
        a1[m4 * 4 + 2] += z1c[jj] * w.z;
        a1[m4 * 4 + 3] += z1c[jj] * w.w;
        a2[m4 * 4 + 0] += z2c[jj] * w.x;
        a2[m4 * 4 + 1] += z2c[jj] * w.y;
        a2[m4 * 4 + 2] += z2c[jj] * w.z;
        a2[m4 * 4 + 3] += z2c[jj] * w.w;
      }
    }
  }
  float sc0 = 0.f, sc1 = 0.f, sc2 = 0.f;
#pragma unroll
  for (int m = 0; m < 16; ++m) {
    float wm = w2s[m], bm = b1s[m];
    sc0 += tanhf(a0[m] + bm) * wm;
    sc1 += tanhf(a1[m] + bm) * wm;
    sc2 += tanhf(a2[m] + bm) * wm;
  }
  float mx = fmaxf(sc0, fmaxf(sc1, sc2));
  float ex0 = expf(sc0 - mx), ex1 = expf(sc1 - mx), ex2 = expf(sc2 - mx);
  float inv = 1.f / (ex0 + ex1 + ex2);
  float be0 = ex0 * inv, be1 = ex1 * inv, be2 = ex2 * inv;
  out_beta[i * 3 + 0] = be0;
  out_beta[i * 3 + 1] = be1;
  out_beta[i * 3 + 2] = be2;

  // pass 2: emb = sum_k beta_k z_k (re-read, L2/L3-hot), logits = emb @ mlp_w + b
  float lg[8];
#pragma unroll
  for (int p = 0; p < 8; ++p) lg[p] = mbs[p];
  float4* oemb = (float4*)out_emb + i * 16;
#pragma unroll
  for (int j4 = 0; j4 < 16; ++j4) {
    float4 z0 = e1[j4], z1 = e2[j4];
    float4 x1 = c1[j4], x2 = c2[j4];
    float4 em;
    em.x = be0 * z0.x + be1 * z1.x + be2 * 0.5f * (x1.x + x2.x);
    em.y = be0 * z0.y + be1 * z1.y + be2 * 0.5f * (x1.y + x2.y);
    em.z = be0 * z0.z + be1 * z1.z + be2 * 0.5f * (x1.z + x2.z);
    em.w = be0 * z0.w + be1 * z1.w + be2 * 0.5f * (x1.w + x2.w);
    oemb[j4] = em;
    float emc[4] = {em.x, em.y, em.z, em.w};
#pragma unroll
    for (int jj = 0; jj < 4; ++jj) {
      int j = j4 * 4 + jj;
      const float4* mrow = (const float4*)(mws + j * 8);
      float4 ma = mrow[0], mb = mrow[1];
      lg[0] += emc[jj] * ma.x;
      lg[1] += emc[jj] * ma.y;
      lg[2] += emc[jj] * ma.z;
      lg[3] += emc[jj] * ma.w;
      lg[4] += emc[jj] * mb.x;
      lg[5] += emc[jj] * mb.y;
      lg[6] += emc[jj] * mb.z;
      lg[7] += emc[jj] * mb.w;
    }
  }
  float m2 = lg[0];
#pragma unroll
  for (int p = 1; p < 8; ++p) m2 = fmaxf(m2, lg[p]);
  float ssum = 0.f;
#pragma unroll
  for (int p = 0; p < 8; ++p) ssum += expf(lg[p] - m2);
  float ls = m2 + logf(ssum);
#pragma unroll
  for (int p = 0; p < 8; ++p) out_logp[i * 8 + p] = lg[p] - ls;
}

extern "C" void kernel_launch(void* const* d_in, const int* in_sizes, int n_in,
                              void* d_out, int out_size, void* d_ws,
                              size_t ws_size, hipStream_t stream) {
  const float* x = (const float*)d_in[0];
  const int* srow = (const int*)d_in[1];
  const int* scol = (const int*)d_in[2];
  const float* sval = (const float*)d_in[3];
  const int* frow = (const int*)d_in[4];
  const int* fcol = (const int*)d_in[5];
  const float* fval = (const float*)d_in[6];
  const float* w_s1_1 = (const float*)d_in[7];
  const float* b_s1_1 = (const float*)d_in[8];
  const float* w_s1_2 = (const float*)d_in[9];
  const float* b_s1_2 = (const float*)d_in[10];
  const float* w_s2_1 = (const float*)d_in[11];
  const float* b_s2_1 = (const float*)d_in[12];
  const float* w_s2_2 = (const float*)d_in[13];
  const float* b_s2_2 = (const float*)d_in[14];
  const float* w_c_1 = (const float*)d_in[15];
  const float* b_c_1 = (const float*)d_in[16];
  const float* w_c_2 = (const float*)d_in[17];
  const float* b_c_2 = (const float*)d_in[18];
  const float* attw1 = (const float*)d_in[19];
  const float* attb1 = (const float*)d_in[20];
  const float* attw2 = (const float*)d_in[21];
  const float* mlpw = (const float*)d_in[22];
  const float* mlpb = (const float*)d_in[23];

  const int n = in_sizes[0] / 128;  // 100000
  const int e = in_sizes[1];        // 1600000

  float* out = (float*)d_out;
  float* o_logp = out;                          // n*8
  float* o_beta = out + (size_t)n * 8;          // n*3
  float* o_emb1 = out + (size_t)n * 11;         // n*64
  float* o_com1 = o_emb1 + (size_t)n * 64;      // n*64
  float* o_com2 = o_com1 + (size_t)n * 64;      // n*64
  float* o_emb2 = o_com2 + (size_t)n * 64;      // n*64
  float* o_emb = o_emb2 + (size_t)n * 64;       // n*64 (written last)

  float* xw = (float*)d_ws;                 // n*128 floats
  float* s = xw + (size_t)n * 128;          // n*128 floats
  float* hw = o_emb;  // reuse 'emb' output region as scratch (final_fuse
                      // overwrites it at the very end)

  const int gemmBlocks = (n + 31) / 32;
  const int spmm128Blocks = (int)(((long)e * 32 + 255) / 256);
  const int spmm64Blocks = (int)(((long)e * 16 + 255) / 256);
  const int biasBlocks = (int)(((long)n * 64 + 255) / 256);

  auto gcn_tail = [&](const int* r, const int* c, const float* v,
                      const float* bb1, const float* w2, const float* bb2,
                      float* dest) {
    hipMemsetAsync(s, 0, (size_t)n * 128 * sizeof(float), stream);
    spmm_atomic<32><<<spmm128Blocks, 256, 0, stream>>>(r, c, v, xw, s, e);
    gemm_relu_128x64<<<gemmBlocks, 256, 0, stream>>>(s, bb1, w2, hw, n);
    init_bias64<<<biasBlocks, 256, 0, stream>>>(dest, bb2, (long)n * 64);
    spmm_atomic<16><<<spmm64Blocks, 256, 0, stream>>>(r, c, v, hw, dest, e);
  };

  // com1, com2 share xw = x @ w_c_1
  gemm_128x128<<<gemmBlocks, 256, 0, stream>>>(x, w_c_1, xw, n);
  gcn_tail(srow, scol, sval, b_c_1, w_c_2, b_c_2, o_com1);
  gcn_tail(frow, fcol, fval, b_c_1, w_c_2, b_c_2, o_com2);

  gemm_128x128<<<gemmBlocks, 256, 0, stream>>>(x, w_s1_1, xw, n);
  gcn_tail(srow, scol, sval, b_s1_1, w_s1_2, b_s1_2, o_emb1);

  gemm_128x128<<<gemmBlocks, 256, 0, stream>>>(x, w_s2_1, xw, n);
  gcn_tail(frow, fcol, fval, b_s2_1, w_s2_2, b_s2_2, o_emb2);

  final_fuse<<<(n + 255) / 256, 256, 0, stream>>>(
      o_emb1, o_emb2, o_com1, o_com2, attw1, attb1, attw2, mlpw, mlpb, o_logp,
      o_beta, o_emb, n);
}

// Round 2
// 3969.142 us; speedup vs baseline: 4.5595x; 4.5595x over previous
//
#include <hip/hip_runtime.h>

// ---------------------------------------------------------------------------
// SFGCN forward on MI355X, round 2: CSR-based gather SpMM (no float atomics).
//
// Per graph: build CSR on device (hist -> scan -> scatter), then per GCN tail:
//   xw = x @ W1                      (gemm_128x128, W staged in LDS)
//   s  = csr_spmm(adj, xw)           (row-parallel gather, split into 2 halves)
//   hw = relu(s + b1) @ W2           (gemm_relu_128x64)
//   dest = b2 + csr_spmm(adj, hw)    (row-parallel gather, bias in registers)
// Final fused attention/softmax/log_softmax epilogue.
//
// d_ws budget (proven-safe 102.4MB in round 1): xw 51.2MB + CSR 14MB +
// spare n*64 region 25.6MB = ~91MB. The 128-feat SpMM output halves live in
// output regions that are not yet finalized (tails carefully ordered).
// ---------------------------------------------------------------------------

#define N_FIXED_BLOCK 256

// C[n][128] = X[n][128] @ W[128][128]; W staged in 64KB LDS.
__global__ __launch_bounds__(256) void gemm_128x128(
    const float* __restrict__ X, const float* __restrict__ W,
    float* __restrict__ C, int nrows) {
  __shared__ __attribute__((aligned(16))) float ws[128 * 128];
  int tid = threadIdx.x;
  const float4* W4 = (const float4*)W;
  float4* ws4 = (float4*)ws;
#pragma unroll
  for (int i = 0; i < 16; ++i) ws4[i * 256 + tid] = W4[i * 256 + tid];
  __syncthreads();

  long row0 = (long)blockIdx.x * 32;
  int c0 = tid & 63;
  int wv = tid >> 6;
  const float* xrow[8];
#pragma unroll
  for (int r = 0; r < 8; ++r) {
    long rr = row0 + wv * 8 + r;
    if (rr > (long)nrows - 1) rr = (long)nrows - 1;
    xrow[r] = X + rr * 128;
  }
  float acc0[8] = {}, acc1[8] = {};
#pragma unroll 4
  for (int k4 = 0; k4 < 32; ++k4) {
    float wa[4], wb[4];
#pragma unroll
    for (int j = 0; j < 4; ++j) {
      wa[j] = ws[(k4 * 4 + j) * 128 + c0];
      wb[j] = ws[(k4 * 4 + j) * 128 + c0 + 64];
    }
#pragma unroll
    for (int r = 0; r < 8; ++r) {
      float4 xv = *(const float4*)(xrow[r] + k4 * 4);
      acc0[r] += xv.x * wa[0] + xv.y * wa[1] + xv.z * wa[2] + xv.w * wa[3];
      acc1[r] += xv.x * wb[0] + xv.y * wb[1] + xv.z * wb[2] + xv.w * wb[3];
    }
  }
#pragma unroll
  for (int r = 0; r < 8; ++r) {
    long rr = row0 + wv * 8 + r;
    if (rr < nrows) {
      C[rr * 128 + c0] = acc0[r];
      C[rr * 128 + c0 + 64] = acc1[r];
    }
  }
}

// ---------------- CSR build ----------------

__global__ __launch_bounds__(256) void hist_kernel(
    const int* __restrict__ row, int* __restrict__ cnt, int e) {
  int i = blockIdx.x * 256 + threadIdx.x;
  if (i < e) atomicAdd(&cnt[row[i]], 1);
}

// Single-block exclusive scan over n counts -> rowptr[n+1] and woff[n].
__global__ __launch_bounds__(1024) void scan_kernel(
    const int* __restrict__ cnt, int* __restrict__ rowptr,
    int* __restrict__ woff, int n) {
  __shared__ int part[1024];
  int tid = threadIdx.x;
  int chunk = (n + 1023) >> 10;
  int lo = tid * chunk;
  int hi = lo + chunk;
  if (hi > n) hi = n;
  int s = 0;
  for (int i = lo; i < hi; ++i) s += cnt[i];
  part[tid] = s;
  __syncthreads();
  for (int d = 1; d < 1024; d <<= 1) {
    int v = (tid >= d) ? part[tid - d] : 0;
    __syncthreads();
    part[tid] += v;
    __syncthreads();
  }
  int base = (tid == 0) ? 0 : part[tid - 1];
  for (int i = lo; i < hi; ++i) {
    rowptr[i] = base;
    woff[i] = base;
    base += cnt[i];
  }
  if (tid == 0) rowptr[n] = part[1023];
}

__global__ __launch_bounds__(256) void scatter_kernel(
    const int* __restrict__ row, const int* __restrict__ col,
    const float* __restrict__ val, int* __restrict__ woff,
    int* __restrict__ scol, float* __restrict__ sval, int e) {
  int i = blockIdx.x * 256 + threadIdx.x;
  if (i >= e) return;
  int r = row[i];
  int p = atomicAdd(&woff[r], 1);
  scol[p] = col[i];
  sval[p] = val[i];
}

// ---------------- CSR SpMM ----------------

// 128 feats: 32 lanes per row (float4 each). Output split into two n*64
// halves OA (feats 0..63) and OB (feats 64..127).
__global__ __launch_bounds__(256) void spmm_csr_128(
    const int* __restrict__ rowptr, const int* __restrict__ scol,
    const float* __restrict__ sval, const float* __restrict__ h,
    float* __restrict__ OA, float* __restrict__ OB, int n) {
  int tid = threadIdx.x;
  int r = blockIdx.x * 8 + (tid >> 5);
  if (r >= n) return;
  int lane = tid & 31;
  int lo = rowptr[r], hi = rowptr[r + 1];
  const float4* h4 = (const float4*)h;
  float4 acc = make_float4(0.f, 0.f, 0.f, 0.f);
  for (int e = lo; e < hi; ++e) {
    float v = sval[e];
    int c = scol[e];
    float4 hv = h4[(long)c * 32 + lane];
    acc.x += v * hv.x;
    acc.y += v * hv.y;
    acc.z += v * hv.z;
    acc.w += v * hv.w;
  }
  if (lane < 16)
    ((float4*)OA)[(long)r * 16 + lane] = acc;
  else
    ((float4*)OB)[(long)r * 16 + (lane - 16)] = acc;
}

// 64 feats: 16 lanes per row, bias as accumulator init, writes dest directly.
__global__ __launch_bounds__(256) void spmm_csr_64(
    const int* __restrict__ rowptr, const int* __restrict__ scol,
    const float* __restrict__ sval, const float* __restrict__ h,
    const float* __restrict__ b2, float* __restrict__ out, int n) {
  int tid = threadIdx.x;
  int r = blockIdx.x * 16 + (tid >> 4);
  if (r >= n) return;
  int lane = tid & 15;
  float4 acc = ((const float4*)b2)[lane];
  int lo = rowptr[r], hi = rowptr[r + 1];
  const float4* h4 = (const float4*)h;
  for (int e = lo; e < hi; ++e) {
    float v = sval[e];
    int c = scol[e];
    float4 hv = h4[(long)c * 16 + lane];
    acc.x += v * hv.x;
    acc.y += v * hv.y;
    acc.z += v * hv.z;
    acc.w += v * hv.w;
  }
  ((float4*)out)[(long)r * 16 + lane] = acc;
}

// H[n][64] = relu(S + b1) @ W2[128][64]; S given as two n*64 halves.
__global__ __launch_bounds__(256) void gemm_relu_128x64(
    const float* __restrict__ SA, const float* __restrict__ SB,
    const float* __restrict__ B1, const float* __restrict__ W2,
    float* __restrict__ H, int nrows) {
  __shared__ __attribute__((aligned(16))) float ws[128 * 64];
  __shared__ __attribute__((aligned(16))) float xs[32 * 128];
  int tid = threadIdx.x;
  const float4* W4 = (const float4*)W2;
  float4* ws4 = (float4*)ws;
#pragma unroll
  for (int i = 0; i < 8; ++i) ws4[i * 256 + tid] = W4[i * 256 + tid];

  long row0 = (long)blockIdx.x * 32;
  const float4* SA4 = (const float4*)SA;
  const float4* SB4 = (const float4*)SB;
  float4* xs4 = (float4*)xs;
#pragma unroll
  for (int i = 0; i < 4; ++i) {
    int flat = i * 256 + tid;  // 0..1023 = 32 rows * 32 f4
    int rl = flat >> 5, f4 = flat & 31;
    long rr = row0 + rl;
    float4 sv = make_float4(0.f, 0.f, 0.f, 0.f);
    if (rr < nrows)
      sv = (f4 < 16) ? SA4[rr * 16 + f4] : SB4[rr * 16 + (f4 - 16)];
    float4 bv = ((const float4*)B1)[f4];
    sv.x = fmaxf(sv.x + bv.x, 0.f);
    sv.y = fmaxf(sv.y + bv.y, 0.f);
    sv.z = fmaxf(sv.z + bv.z, 0.f);
    sv.w = fmaxf(sv.w + bv.w, 0.f);
    xs4[flat] = sv;
  }
  __syncthreads();

  int c = tid & 63;
  int wv = tid >> 6;
  const float* xrow = xs + wv * 8 * 128;
  float acc[8] = {};
#pragma unroll 4
  for (int k4 = 0; k4 < 32; ++k4) {
    float wk[4];
#pragma unroll
    for (int j = 0; j < 4; ++j) wk[j] = ws[(k4 * 4 + j) * 64 + c];
#pragma unroll
    for (int r = 0; r < 8; ++r) {
      float4 xv = *(const float4*)(xrow + r * 128 + k4 * 4);
      acc[r] += xv.x * wk[0] + xv.y * wk[1] + xv.z * wk[2] + xv.w * wk[3];
    }
  }
#pragma unroll
  for (int r = 0; r < 8; ++r) {
    long rr = row0 + wv * 8 + r;
    if (rr < nrows) H[rr * 64 + c] = acc[r];
  }
}

// Fused attention + softmax + emb + log_softmax epilogue. One thread per node.
__global__ __launch_bounds__(256) void final_fuse(
    const float* __restrict__ emb1, const float* __restrict__ emb2,
    const float* __restrict__ com1, const float* __restrict__ com2,
    const float* __restrict__ attw1, const float* __restrict__ attb1,
    const float* __restrict__ attw2, const float* __restrict__ mlpw,
    const float* __restrict__ mlpb, float* __restrict__ out_logp,
    float* __restrict__ out_beta, float* __restrict__ out_emb, int n) {
  __shared__ __attribute__((aligned(16))) float w1s[64 * 16];
  __shared__ __attribute__((aligned(16))) float mws[64 * 8];
  __shared__ float b1s[16];
  __shared__ float w2s[16];
  __shared__ float mbs[8];
  int tid = threadIdx.x;
  for (int i = tid; i < 1024; i += 256) w1s[i] = attw1[i];
  for (int i = tid; i < 512; i += 256) mws[i] = mlpw[i];
  if (tid < 16) {
    b1s[tid] = attb1[tid];
    w2s[tid] = attw2[tid];
  }
  if (tid < 8) mbs[tid] = mlpb[tid];
  __syncthreads();

  long i = (long)blockIdx.x * 256 + tid;
  if (i >= n) return;
  const float4* e1 = (const float4*)emb1 + i * 16;
  const float4* e2 = (const float4*)emb2 + i * 16;
  const float4* c1 = (const float4*)com1 + i * 16;
  const float4* c2 = (const float4*)com2 + i * 16;

  float a0[16] = {}, a1[16] = {}, a2[16] = {};
#pragma unroll
  for (int j4 = 0; j4 < 16; ++j4) {
    float4 z0 = e1[j4], z1 = e2[j4];
    float4 x1 = c1[j4], x2 = c2[j4];
    float z0c[4] = {z0.x, z0.y, z0.z, z0.w};
    float z1c[4] = {z1.x, z1.y, z1.z, z1.w};
    float z2c[4] = {0.5f * (x1.x + x2.x), 0.5f * (x1.y + x2.y),
                    0.5f * (x1.z + x2.z), 0.5f * (x1.w + x2.w)};
#pragma unroll
    for (int jj = 0; jj < 4; ++jj) {
      int j = j4 * 4 + jj;
      const float4* wrow = (const float4*)(w1s + j * 16);
#pragma unroll
      for (int m4 = 0; m4 < 4; ++m4) {
        float4 w = wrow[m4];
        a0[m4 * 4 + 0] += z0c[jj] * w.x;
        a0[m4 * 4 + 1] += z0c[jj] * w.y;
        a0[m4 * 4 + 2] += z0c[jj] * w.z;
        a0[m4 * 4 + 3] += z0c[jj] * w.w;
        a1[m4 * 4 + 0] += z1c[jj] * w.x;
        a1[m4 * 4 + 1] += z1c[jj] * w.y;
        a1[m4 * 4 + 2] += z1c[jj] * w.z;
        a1[m4 * 4 + 3] += z1c[jj] * w.w;
        a2[m4 * 4 + 0] += z2c[jj] * w.x;
        a2[m4 * 4 + 1] += z2c[jj] * w.y;
        a2[m4 * 4 + 2] += z2c[jj] * w.z;
        a2[m4 * 4 + 3] += z2c[jj] * w.w;
      }
    }
  }
  float sc0 = 0.f, sc1 = 0.f, sc2 = 0.f;
#pragma unroll
  for (int m = 0; m < 16; ++m) {
    float wm = w2s[m], bm = b1s[m];
    sc0 += tanhf(a0[m] + bm) * wm;
    sc1 += tanhf(a1[m] + bm) * wm;
    sc2 += tanhf(a2[m] + bm) * wm;
  }
  float mx = fmaxf(sc0, fmaxf(sc1, sc2));
  float ex0 = expf(sc0 - mx), ex1 = expf(sc1 - mx), ex2 = expf(sc2 - mx);
  float inv = 1.f / (ex0 + ex1 + ex2);
  float be0 = ex0 * inv, be1 = ex1 * inv, be2 = ex2 * inv;
  out_beta[i * 3 + 0] = be0;
  out_beta[i * 3 + 1] = be1;
  out_beta[i * 3 + 2] = be2;

  float lg[8];
#pragma unroll
  for (int p = 0; p < 8; ++p) lg[p] = mbs[p];
  float4* oemb = (float4*)out_emb + i * 16;
#pragma unroll
  for (int j4 = 0; j4 < 16; ++j4) {
    float4 z0 = e1[j4], z1 = e2[j4];
    float4 x1 = c1[j4], x2 = c2[j4];
    float4 em;
    em.x = be0 * z0.x + be1 * z1.x + be2 * 0.5f * (x1.x + x2.x);
    em.y = be0 * z0.y + be1 * z1.y + be2 * 0.5f * (x1.y + x2.y);
    em.z = be0 * z0.z + be1 * z1.z + be2 * 0.5f * (x1.z + x2.z);
    em.w = be0 * z0.w + be1 * z1.w + be2 * 0.5f * (x1.w + x2.w);
    oemb[j4] = em;
    float emc[4] = {em.x, em.y, em.z, em.w};
#pragma unroll
    for (int jj = 0; jj < 4; ++jj) {
      int j = j4 * 4 + jj;
      const float4* mrow = (const float4*)(mws + j * 8);
      float4 ma = mrow[0], mb = mrow[1];
      lg[0] += emc[jj] * ma.x;
      lg[1] += emc[jj] * ma.y;
      lg[2] += emc[jj] * ma.z;
      lg[3] += emc[jj] * ma.w;
      lg[4] += emc[jj] * mb.x;
      lg[5] += emc[jj] * mb.y;
      lg[6] += emc[jj] * mb.z;
      lg[7] += emc[jj] * mb.w;
    }
  }
  float m2 = lg[0];
#pragma unroll
  for (int p = 1; p < 8; ++p) m2 = fmaxf(m2, lg[p]);
  float ssum = 0.f;
#pragma unroll
  for (int p = 0; p < 8; ++p) ssum += expf(lg[p] - m2);
  float ls = m2 + logf(ssum);
#pragma unroll
  for (int p = 0; p < 8; ++p) out_logp[i * 8 + p] = lg[p] - ls;
}

extern "C" void kernel_launch(void* const* d_in, const int* in_sizes, int n_in,
                              void* d_out, int out_size, void* d_ws,
                              size_t ws_size, hipStream_t stream) {
  const float* x = (const float*)d_in[0];
  const int* srow = (const int*)d_in[1];
  const int* scol_in = (const int*)d_in[2];
  const float* sval_in = (const float*)d_in[3];
  const int* frow = (const int*)d_in[4];
  const int* fcol_in = (const int*)d_in[5];
  const float* fval_in = (const float*)d_in[6];
  const float* w_s1_1 = (const float*)d_in[7];
  const float* b_s1_1 = (const float*)d_in[8];
  const float* w_s1_2 = (const float*)d_in[9];
  const float* b_s1_2 = (const float*)d_in[10];
  const float* w_s2_1 = (const float*)d_in[11];
  const float* b_s2_1 = (const float*)d_in[12];
  const float* w_s2_2 = (const float*)d_in[13];
  const float* b_s2_2 = (const float*)d_in[14];
  const float* w_c_1 = (const float*)d_in[15];
  const float* b_c_1 = (const float*)d_in[16];
  const float* w_c_2 = (const float*)d_in[17];
  const float* b_c_2 = (const float*)d_in[18];
  const float* attw1 = (const float*)d_in[19];
  const float* attb1 = (const float*)d_in[20];
  const float* attw2 = (const float*)d_in[21];
  const float* mlpw = (const float*)d_in[22];
  const float* mlpb = (const float*)d_in[23];

  const int n = in_sizes[0] / 128;  // 100000
  const int e = in_sizes[1];        // 1600000

  float* out = (float*)d_out;
  float* o_logp = out;
  float* o_beta = out + (size_t)n * 8;
  float* o_emb1 = out + (size_t)n * 11;
  float* o_com1 = o_emb1 + (size_t)n * 64;
  float* o_com2 = o_com1 + (size_t)n * 64;
  float* o_emb2 = o_com2 + (size_t)n * 64;
  float* o_emb = o_emb2 + (size_t)n * 64;

  // workspace layout
  float* xw = (float*)d_ws;                       // n*128 floats
  int* cnt = (int*)(xw + (size_t)n * 128);        // n
  int* rowptr = cnt + n;                          // n+1
  int* woff = rowptr + n + 1;                     // n
  int* g_col = woff + n;                          // e
  float* g_val = (float*)(g_col + e);             // e
  float* sB_ws = g_val + e;                       // n*64 spare region

  float* hw = o_emb;  // final_fuse overwrites at the end

  const int gemmBlocks = (n + 31) / 32;
  const int histBlocks = (e + 255) / 256;
  const int spmm128Blocks = (n + 7) / 8;
  const int spmm64Blocks = (n + 15) / 16;

  auto build_csr = [&](const int* r, const int* c, const float* v) {
    hipMemsetAsync(cnt, 0, (size_t)n * sizeof(int), stream);
    hist_kernel<<<histBlocks, 256, 0, stream>>>(r, cnt, e);
    scan_kernel<<<1, 1024, 0, stream>>>(cnt, rowptr, woff, n);
    scatter_kernel<<<histBlocks, 256, 0, stream>>>(r, c, v, woff, g_col,
                                                   g_val, e);
  };

  auto gcn_tail = [&](const float* w1, const float* bb1, const float* w2,
                      const float* bb2, float* dest, float* sA, float* sB) {
    gemm_128x128<<<gemmBlocks, 256, 0, stream>>>(x, w1, xw, n);
    spmm_csr_128<<<spmm128Blocks, 256, 0, stream>>>(rowptr, g_col, g_val, xw,
                                                    sA, sB, n);
    gemm_relu_128x64<<<gemmBlocks, 256, 0, stream>>>(sA, sB, bb1, w2, hw, n);
    spmm_csr_64<<<spmm64Blocks, 256, 0, stream>>>(rowptr, g_col, g_val, hw,
                                                  bb2, dest, n);
  };

  // graph sadj: emb1 (w_s1), com1 (w_c)
  build_csr(srow, scol_in, sval_in);
  gcn_tail(w_s1_1, b_s1_1, w_s1_2, b_s1_2, o_emb1, o_com1, o_com2);
  gcn_tail(w_c_1, b_c_1, w_c_2, b_c_2, o_com1, o_com2, o_emb2);

  // graph fadj: com2 (w_c), emb2 (w_s2)
  build_csr(frow, fcol_in, fval_in);
  gcn_tail(w_c_1, b_c_1, w_c_2, b_c_2, o_com2, o_emb2, sB_ws);
  gcn_tail(w_s2_1, b_s2_1, w_s2_2, b_s2_2, o_emb2, o_emb2, sB_ws);

  final_fuse<<<(n + 255) / 256, 256, 0, stream>>>(
      o_emb1, o_emb2, o_com1, o_com2, attw1, attb1, attw2, mlpw, mlpb, o_logp,
      o_beta, o_emb, n);
}

// Round 3
// 2656.674 us; speedup vs baseline: 6.8119x; 1.4940x over previous
//
#include <hip/hip_runtime.h>

// ---------------------------------------------------------------------------
// SFGCN forward on MI355X, round 3: CSR gather SpMM + wave-cooperative
// final_fuse (16 lanes per node; coalesced loads; shfl_xor reductions).
// ---------------------------------------------------------------------------

// C[n][128] = X[n][128] @ W[128][128]; W staged in 64KB LDS.
__global__ __launch_bounds__(256) void gemm_128x128(
    const float* __restrict__ X, const float* __restrict__ W,
    float* __restrict__ C, int nrows) {
  __shared__ __attribute__((aligned(16))) float ws[128 * 128];
  int tid = threadIdx.x;
  const float4* W4 = (const float4*)W;
  float4* ws4 = (float4*)ws;
#pragma unroll
  for (int i = 0; i < 16; ++i) ws4[i * 256 + tid] = W4[i * 256 + tid];
  __syncthreads();

  long row0 = (long)blockIdx.x * 32;
  int c0 = tid & 63;
  int wv = tid >> 6;
  const float* xrow[8];
#pragma unroll
  for (int r = 0; r < 8; ++r) {
    long rr = row0 + wv * 8 + r;
    if (rr > (long)nrows - 1) rr = (long)nrows - 1;
    xrow[r] = X + rr * 128;
  }
  float acc0[8] = {}, acc1[8] = {};
#pragma unroll 4
  for (int k4 = 0; k4 < 32; ++k4) {
    float wa[4], wb[4];
#pragma unroll
    for (int j = 0; j < 4; ++j) {
      wa[j] = ws[(k4 * 4 + j) * 128 + c0];
      wb[j] = ws[(k4 * 4 + j) * 128 + c0 + 64];
    }
#pragma unroll
    for (int r = 0; r < 8; ++r) {
      float4 xv = *(const float4*)(xrow[r] + k4 * 4);
      acc0[r] += xv.x * wa[0] + xv.y * wa[1] + xv.z * wa[2] + xv.w * wa[3];
      acc1[r] += xv.x * wb[0] + xv.y * wb[1] + xv.z * wb[2] + xv.w * wb[3];
    }
  }
#pragma unroll
  for (int r = 0; r < 8; ++r) {
    long rr = row0 + wv * 8 + r;
    if (rr < nrows) {
      C[rr * 128 + c0] = acc0[r];
      C[rr * 128 + c0 + 64] = acc1[r];
    }
  }
}

// ---------------- CSR build ----------------

__global__ __launch_bounds__(256) void hist_kernel(
    const int* __restrict__ row, int* __restrict__ cnt, int e) {
  int i = blockIdx.x * 256 + threadIdx.x;
  if (i < e) atomicAdd(&cnt[row[i]], 1);
}

__global__ __launch_bounds__(1024) void scan_kernel(
    const int* __restrict__ cnt, int* __restrict__ rowptr,
    int* __restrict__ woff, int n) {
  __shared__ int part[1024];
  int tid = threadIdx.x;
  int chunk = (n + 1023) >> 10;
  int lo = tid * chunk;
  int hi = lo + chunk;
  if (hi > n) hi = n;
  int s = 0;
  for (int i = lo; i < hi; ++i) s += cnt[i];
  part[tid] = s;
  __syncthreads();
  for (int d = 1; d < 1024; d <<= 1) {
    int v = (tid >= d) ? part[tid - d] : 0;
    __syncthreads();
    part[tid] += v;
    __syncthreads();
  }
  int base = (tid == 0) ? 0 : part[tid - 1];
  for (int i = lo; i < hi; ++i) {
    rowptr[i] = base;
    woff[i] = base;
    base += cnt[i];
  }
  if (tid == 0) rowptr[n] = part[1023];
}

__global__ __launch_bounds__(256) void scatter_kernel(
    const int* __restrict__ row, const int* __restrict__ col,
    const float* __restrict__ val, int* __restrict__ woff,
    int* __restrict__ scol, float* __restrict__ sval, int e) {
  int i = blockIdx.x * 256 + threadIdx.x;
  if (i >= e) return;
  int r = row[i];
  int p = atomicAdd(&woff[r], 1);
  scol[p] = col[i];
  sval[p] = val[i];
}

// ---------------- CSR SpMM ----------------

__global__ __launch_bounds__(256) void spmm_csr_128(
    const int* __restrict__ rowptr, const int* __restrict__ scol,
    const float* __restrict__ sval, const float* __restrict__ h,
    float* __restrict__ OA, float* __restrict__ OB, int n) {
  int tid = threadIdx.x;
  int r = blockIdx.x * 8 + (tid >> 5);
  if (r >= n) return;
  int lane = tid & 31;
  int lo = rowptr[r], hi = rowptr[r + 1];
  const float4* h4 = (const float4*)h;
  float4 acc = make_float4(0.f, 0.f, 0.f, 0.f);
  for (int e = lo; e < hi; ++e) {
    float v = sval[e];
    int c = scol[e];
    float4 hv = h4[(long)c * 32 + lane];
    acc.x += v * hv.x;
    acc.y += v * hv.y;
    acc.z += v * hv.z;
    acc.w += v * hv.w;
  }
  if (lane < 16)
    ((float4*)OA)[(long)r * 16 + lane] = acc;
  else
    ((float4*)OB)[(long)r * 16 + (lane - 16)] = acc;
}

__global__ __launch_bounds__(256) void spmm_csr_64(
    const int* __restrict__ rowptr, const int* __restrict__ scol,
    const float* __restrict__ sval, const float* __restrict__ h,
    const float* __restrict__ b2, float* __restrict__ out, int n) {
  int tid = threadIdx.x;
  int r = blockIdx.x * 16 + (tid >> 4);
  if (r >= n) return;
  int lane = tid & 15;
  float4 acc = ((const float4*)b2)[lane];
  int lo = rowptr[r], hi = rowptr[r + 1];
  const float4* h4 = (const float4*)h;
  for (int e = lo; e < hi; ++e) {
    float v = sval[e];
    int c = scol[e];
    float4 hv = h4[(long)c * 16 + lane];
    acc.x += v * hv.x;
    acc.y += v * hv.y;
    acc.z += v * hv.z;
    acc.w += v * hv.w;
  }
  ((float4*)out)[(long)r * 16 + lane] = acc;
}

// H[n][64] = relu(S + b1) @ W2[128][64]; S given as two n*64 halves.
__global__ __launch_bounds__(256) void gemm_relu_128x64(
    const float* __restrict__ SA, const float* __restrict__ SB,
    const float* __restrict__ B1, const float* __restrict__ W2,
    float* __restrict__ H, int nrows) {
  __shared__ __attribute__((aligned(16))) float ws[128 * 64];
  __shared__ __attribute__((aligned(16))) float xs[32 * 128];
  int tid = threadIdx.x;
  const float4* W4 = (const float4*)W2;
  float4* ws4 = (float4*)ws;
#pragma unroll
  for (int i = 0; i < 8; ++i) ws4[i * 256 + tid] = W4[i * 256 + tid];

  long row0 = (long)blockIdx.x * 32;
  const float4* SA4 = (const float4*)SA;
  const float4* SB4 = (const float4*)SB;
  float4* xs4 = (float4*)xs;
#pragma unroll
  for (int i = 0; i < 4; ++i) {
    int flat = i * 256 + tid;
    int rl = flat >> 5, f4 = flat & 31;
    long rr = row0 + rl;
    float4 sv = make_float4(0.f, 0.f, 0.f, 0.f);
    if (rr < nrows)
      sv = (f4 < 16) ? SA4[rr * 16 + f4] : SB4[rr * 16 + (f4 - 16)];
    float4 bv = ((const float4*)B1)[f4];
    sv.x = fmaxf(sv.x + bv.x, 0.f);
    sv.y = fmaxf(sv.y + bv.y, 0.f);
    sv.z = fmaxf(sv.z + bv.z, 0.f);
    sv.w = fmaxf(sv.w + bv.w, 0.f);
    xs4[flat] = sv;
  }
  __syncthreads();

  int c = tid & 63;
  int wv = tid >> 6;
  const float* xrow = xs + wv * 8 * 128;
  float acc[8] = {};
#pragma unroll 4
  for (int k4 = 0; k4 < 32; ++k4) {
    float wk[4];
#pragma unroll
    for (int j = 0; j < 4; ++j) wk[j] = ws[(k4 * 4 + j) * 64 + c];
#pragma unroll
    for (int r = 0; r < 8; ++r) {
      float4 xv = *(const float4*)(xrow + r * 128 + k4 * 4);
      acc[r] += xv.x * wk[0] + xv.y * wk[1] + xv.z * wk[2] + xv.w * wk[3];
    }
  }
#pragma unroll
  for (int r = 0; r < 8; ++r) {
    long rr = row0 + wv * 8 + r;
    if (rr < nrows) H[rr * 64 + c] = acc[r];
  }
}

// ---------------- final fuse (wave-cooperative: 16 lanes per node) --------
// Lane l of a 16-lane group holds feats [4l, 4l+4) of its node in registers.
// Loads are coalesced (wave = 4 consecutive nodes, contiguous 1KB).
// Reductions: shfl_xor butterflies over d=1,2,4,8 (stay in-group).
__global__ __launch_bounds__(256) void final_fuse(
    const float* __restrict__ emb1, const float* __restrict__ emb2,
    const float* __restrict__ com1, const float* __restrict__ com2,
    const float* __restrict__ attw1, const float* __restrict__ attb1,
    const float* __restrict__ attw2, const float* __restrict__ mlpw,
    const float* __restrict__ mlpb, float* __restrict__ out_logp,
    float* __restrict__ out_beta, float* __restrict__ out_emb, int n) {
  __shared__ __attribute__((aligned(16))) float w1t[16][64];  // attw1^T
  __shared__ __attribute__((aligned(16))) float mwt[8][64];   // mlpw^T
  __shared__ float b1s[16];
  __shared__ float w2s[16];
  __shared__ float mbs[8];
  int tid = threadIdx.x;
  for (int idx = tid; idx < 1024; idx += 256)
    w1t[idx & 15][idx >> 4] = attw1[idx];  // attw1[f][m] -> w1t[m][f]
  for (int idx = tid; idx < 512; idx += 256)
    mwt[idx & 7][idx >> 3] = mlpw[idx];    // mlpw[f][p] -> mwt[p][f]
  if (tid < 16) {
    b1s[tid] = attb1[tid];
    w2s[tid] = attw2[tid];
  }
  if (tid < 8) mbs[tid] = mlpb[tid];
  __syncthreads();

  int lane = tid & 15;
  long i = ((long)blockIdx.x * 256 + tid) >> 4;  // node id
  bool alive = i < n;
  long ii = alive ? i : (long)(n - 1);

  float4 z0 = ((const float4*)emb1)[ii * 16 + lane];
  float4 z1 = ((const float4*)emb2)[ii * 16 + lane];
  float4 x1 = ((const float4*)com1)[ii * 16 + lane];
  float4 x2 = ((const float4*)com2)[ii * 16 + lane];
  float4 z2 = make_float4(0.5f * (x1.x + x2.x), 0.5f * (x1.y + x2.y),
                          0.5f * (x1.z + x2.z), 0.5f * (x1.w + x2.w));

  // a_k[m] partials: dot(z_k[lane*4..], w1t[m][lane*4..])
  float a0[16], a1[16], a2[16];
#pragma unroll
  for (int m = 0; m < 16; ++m) {
    float4 w = *(const float4*)&w1t[m][lane * 4];
    a0[m] = z0.x * w.x + z0.y * w.y + z0.z * w.z + z0.w * w.w;
    a1[m] = z1.x * w.x + z1.y * w.y + z1.z * w.z + z1.w * w.w;
    a2[m] = z2.x * w.x + z2.y * w.y + z2.z * w.z + z2.w * w.w;
  }
  // reduce across the 16-lane group (xor 1,2,4,8 stay in-group)
#pragma unroll
  for (int d = 1; d < 16; d <<= 1) {
#pragma unroll
    for (int m = 0; m < 16; ++m) {
      a0[m] += __shfl_xor(a0[m], d);
      a1[m] += __shfl_xor(a1[m], d);
      a2[m] += __shfl_xor(a2[m], d);
    }
  }
  float sc0 = 0.f, sc1 = 0.f, sc2 = 0.f;
#pragma unroll
  for (int m = 0; m < 16; ++m) {
    float wm = w2s[m], bm = b1s[m];
    sc0 += tanhf(a0[m] + bm) * wm;
    sc1 += tanhf(a1[m] + bm) * wm;
    sc2 += tanhf(a2[m] + bm) * wm;
  }
  float mx = fmaxf(sc0, fmaxf(sc1, sc2));
  float ex0 = expf(sc0 - mx), ex1 = expf(sc1 - mx), ex2 = expf(sc2 - mx);
  float inv = 1.f / (ex0 + ex1 + ex2);
  float be0 = ex0 * inv, be1 = ex1 * inv, be2 = ex2 * inv;

  // emb (lane-local)
  float4 em;
  em.x = be0 * z0.x + be1 * z1.x + be2 * z2.x;
  em.y = be0 * z0.y + be1 * z1.y + be2 * z2.y;
  em.z = be0 * z0.z + be1 * z1.z + be2 * z2.z;
  em.w = be0 * z0.w + be1 * z1.w + be2 * z2.w;
  if (alive) ((float4*)out_emb)[i * 16 + lane] = em;

  // logits partials + reduce
  float lg[8];
#pragma unroll
  for (int p = 0; p < 8; ++p) {
    float4 w = *(const float4*)&mwt[p][lane * 4];
    lg[p] = em.x * w.x + em.y * w.y + em.z * w.z + em.w * w.w;
  }
#pragma unroll
  for (int d = 1; d < 16; d <<= 1) {
#pragma unroll
    for (int p = 0; p < 8; ++p) lg[p] += __shfl_xor(lg[p], d);
  }
#pragma unroll
  for (int p = 0; p < 8; ++p) lg[p] += mbs[p];
  float m2 = lg[0];
#pragma unroll
  for (int p = 1; p < 8; ++p) m2 = fmaxf(m2, lg[p]);
  float ssum = 0.f;
#pragma unroll
  for (int p = 0; p < 8; ++p) ssum += expf(lg[p] - m2);
  float ls = m2 + logf(ssum);

  if (alive && lane == 0) {
    float4 o0 = make_float4(lg[0] - ls, lg[1] - ls, lg[2] - ls, lg[3] - ls);
    float4 o1 = make_float4(lg[4] - ls, lg[5] - ls, lg[6] - ls, lg[7] - ls);
    *(float4*)&out_logp[i * 8] = o0;
    *(float4*)&out_logp[i * 8 + 4] = o1;
    out_beta[i * 3 + 0] = be0;
    out_beta[i * 3 + 1] = be1;
    out_beta[i * 3 + 2] = be2;
  }
}

extern "C" void kernel_launch(void* const* d_in, const int* in_sizes, int n_in,
                              void* d_out, int out_size, void* d_ws,
                              size_t ws_size, hipStream_t stream) {
  const float* x = (const float*)d_in[0];
  const int* srow = (const int*)d_in[1];
  const int* scol_in = (const int*)d_in[2];
  const float* sval_in = (const float*)d_in[3];
  const int* frow = (const int*)d_in[4];
  const int* fcol_in = (const int*)d_in[5];
  const float* fval_in = (const float*)d_in[6];
  const float* w_s1_1 = (const float*)d_in[7];
  const float* b_s1_1 = (const float*)d_in[8];
  const float* w_s1_2 = (const float*)d_in[9];
  const float* b_s1_2 = (const float*)d_in[10];
  const float* w_s2_1 = (const float*)d_in[11];
  const float* b_s2_1 = (const float*)d_in[12];
  const float* w_s2_2 = (const float*)d_in[13];
  const float* b_s2_2 = (const float*)d_in[14];
  const float* w_c_1 = (const float*)d_in[15];
  const float* b_c_1 = (const float*)d_in[16];
  const float* w_c_2 = (const float*)d_in[17];
  const float* b_c_2 = (const float*)d_in[18];
  const float* attw1 = (const float*)d_in[19];
  const float* attb1 = (const float*)d_in[20];
  const float* attw2 = (const float*)d_in[21];
  const float* mlpw = (const float*)d_in[22];
  const float* mlpb = (const float*)d_in[23];

  const int n = in_sizes[0] / 128;  // 100000
  const int e = in_sizes[1];        // 1600000

  float* out = (float*)d_out;
  float* o_logp = out;
  float* o_beta = out + (size_t)n * 8;
  float* o_emb1 = out + (size_t)n * 11;
  float* o_com1 = o_emb1 + (size_t)n * 64;
  float* o_com2 = o_com1 + (size_t)n * 64;
  float* o_emb2 = o_com2 + (size_t)n * 64;
  float* o_emb = o_emb2 + (size_t)n * 64;

  // workspace layout
  float* xw = (float*)d_ws;                       // n*128 floats
  int* cnt = (int*)(xw + (size_t)n * 128);        // n
  int* rowptr = cnt + n;                          // n+1
  int* woff = rowptr + n + 1;                     // n
  int* g_col = woff + n;                          // e
  float* g_val = (float*)(g_col + e);             // e
  float* sB_ws = g_val + e;                       // n*64 spare region

  float* hw = o_emb;  // final_fuse overwrites at the end

  const int gemmBlocks = (n + 31) / 32;
  const int histBlocks = (e + 255) / 256;
  const int spmm128Blocks = (n + 7) / 8;
  const int spmm64Blocks = (n + 15) / 16;

  auto build_csr = [&](const int* r, const int* c, const float* v) {
    hipMemsetAsync(cnt, 0, (size_t)n * sizeof(int), stream);
    hist_kernel<<<histBlocks, 256, 0, stream>>>(r, cnt, e);
    scan_kernel<<<1, 1024, 0, stream>>>(cnt, rowptr, woff, n);
    scatter_kernel<<<histBlocks, 256, 0, stream>>>(r, c, v, woff, g_col,
                                                   g_val, e);
  };

  auto gcn_tail = [&](const float* w1, const float* bb1, const float* w2,
                      const float* bb2, float* dest, float* sA, float* sB) {
    gemm_128x128<<<gemmBlocks, 256, 0, stream>>>(x, w1, xw, n);
    spmm_csr_128<<<spmm128Blocks, 256, 0, stream>>>(rowptr, g_col, g_val, xw,
                                                    sA, sB, n);
    gemm_relu_128x64<<<gemmBlocks, 256, 0, stream>>>(sA, sB, bb1, w2, hw, n);
    spmm_csr_64<<<spmm64Blocks, 256, 0, stream>>>(rowptr, g_col, g_val, hw,
                                                  bb2, dest, n);
  };

  // graph sadj: emb1 (w_s1), com1 (w_c)
  build_csr(srow, scol_in, sval_in);
  gcn_tail(w_s1_1, b_s1_1, w_s1_2, b_s1_2, o_emb1, o_com1, o_com2);
  gcn_tail(w_c_1, b_c_1, w_c_2, b_c_2, o_com1, o_com2, o_emb2);

  // graph fadj: com2 (w_c), emb2 (w_s2)
  build_csr(frow, fcol_in, fval_in);
  gcn_tail(w_c_1, b_c_1, w_c_2, b_c_2, o_com2, o_emb2, sB_ws);
  gcn_tail(w_s2_1, b_s2_1, w_s2_2, b_s2_2, o_emb2, o_emb2, sB_ws);

  final_fuse<<<(int)(((long)n * 16 + 255) / 256), 256, 0, stream>>>(
      o_emb1, o_emb2, o_com1, o_com2, attw1, attb1, attw2, mlpw, mlpb, o_logp,
      o_beta, o_emb, n);
}

// Round 4
// 2225.264 us; speedup vs baseline: 8.1326x; 1.1939x over previous
//
#include <hip/hip_runtime.h>

// ---------------------------------------------------------------------------
// SFGCN forward on MI355X, round 4: CSR gather SpMM + wave-cooperative
// final_fuse + hierarchical 3-phase CSR scan (replaces 230us single-block scan).
// ---------------------------------------------------------------------------

// C[n][128] = X[n][128] @ W[128][128]; W staged in 64KB LDS.
__global__ __launch_bounds__(256) void gemm_128x128(
    const float* __restrict__ X, const float* __restrict__ W,
    float* __restrict__ C, int nrows) {
  __shared__ __attribute__((aligned(16))) float ws[128 * 128];
  int tid = threadIdx.x;
  const float4* W4 = (const float4*)W;
  float4* ws4 = (float4*)ws;
#pragma unroll
  for (int i = 0; i < 16; ++i) ws4[i * 256 + tid] = W4[i * 256 + tid];
  __syncthreads();

  long row0 = (long)blockIdx.x * 32;
  int c0 = tid & 63;
  int wv = tid >> 6;
  const float* xrow[8];
#pragma unroll
  for (int r = 0; r < 8; ++r) {
    long rr = row0 + wv * 8 + r;
    if (rr > (long)nrows - 1) rr = (long)nrows - 1;
    xrow[r] = X + rr * 128;
  }
  float acc0[8] = {}, acc1[8] = {};
#pragma unroll 4
  for (int k4 = 0; k4 < 32; ++k4) {
    float wa[4], wb[4];
#pragma unroll
    for (int j = 0; j < 4; ++j) {
      wa[j] = ws[(k4 * 4 + j) * 128 + c0];
      wb[j] = ws[(k4 * 4 + j) * 128 + c0 + 64];
    }
#pragma unroll
    for (int r = 0; r < 8; ++r) {
      float4 xv = *(const float4*)(xrow[r] + k4 * 4);
      acc0[r] += xv.x * wa[0] + xv.y * wa[1] + xv.z * wa[2] + xv.w * wa[3];
      acc1[r] += xv.x * wb[0] + xv.y * wb[1] + xv.z * wb[2] + xv.w * wb[3];
    }
  }
#pragma unroll
  for (int r = 0; r < 8; ++r) {
    long rr = row0 + wv * 8 + r;
    if (rr < nrows) {
      C[rr * 128 + c0] = acc0[r];
      C[rr * 128 + c0 + 64] = acc1[r];
    }
  }
}

// ---------------- CSR build ----------------

__global__ __launch_bounds__(256) void hist_kernel(
    const int* __restrict__ row, int* __restrict__ cnt, int e) {
  int i = blockIdx.x * 256 + threadIdx.x;
  if (i < e) atomicAdd(&cnt[row[i]], 1);
}

// Phase A: per-tile (1024 counts) sums. grid = ceil(n/1024), block = 256.
__global__ __launch_bounds__(256) void scan_partial(
    const int* __restrict__ cnt, int* __restrict__ part, int n) {
  __shared__ int red[256];
  int t = threadIdx.x;
  int base = blockIdx.x * 1024 + t * 4;
  int s = 0;
#pragma unroll
  for (int j = 0; j < 4; ++j) {
    int idx = base + j;
    if (idx < n) s += cnt[idx];
  }
  red[t] = s;
  __syncthreads();
#pragma unroll
  for (int d = 128; d > 0; d >>= 1) {
    if (t < d) red[t] += red[t + d];
    __syncthreads();
  }
  if (t == 0) part[blockIdx.x] = red[0];
}

// Phase B: single small block scans nb partials (exclusive, in place).
__global__ __launch_bounds__(256) void scan_tops(int* __restrict__ part,
                                                 int nb) {
  __shared__ int lds[256];
  int t = threadIdx.x;
  lds[t] = (t < nb) ? part[t] : 0;
  __syncthreads();
#pragma unroll
  for (int d = 1; d < 256; d <<= 1) {
    int v = (t >= d) ? lds[t - d] : 0;
    __syncthreads();
    lds[t] += v;
    __syncthreads();
  }
  if (t < nb) part[t] = (t == 0) ? 0 : lds[t - 1];
}

// Phase C: rescan tile with global offset; write rowptr + woff.
__global__ __launch_bounds__(256) void scan_final(
    const int* __restrict__ cnt, const int* __restrict__ part,
    int* __restrict__ rowptr, int* __restrict__ woff, int n, int e) {
  __shared__ int lds[256];
  int t = threadIdx.x;
  int base = blockIdx.x * 1024 + t * 4;
  int c[4];
  int s = 0;
#pragma unroll
  for (int j = 0; j < 4; ++j) {
    int idx = base + j;
    c[j] = (idx < n) ? cnt[idx] : 0;
    s += c[j];
  }
  lds[t] = s;
  __syncthreads();
#pragma unroll
  for (int d = 1; d < 256; d <<= 1) {
    int v = (t >= d) ? lds[t - d] : 0;
    __syncthreads();
    lds[t] += v;
    __syncthreads();
  }
  int off = part[blockIdx.x] + ((t == 0) ? 0 : lds[t - 1]);
#pragma unroll
  for (int j = 0; j < 4; ++j) {
    int idx = base + j;
    if (idx < n) {
      rowptr[idx] = off;
      woff[idx] = off;
      off += c[j];
    }
  }
  if (blockIdx.x == 0 && t == 0) rowptr[n] = e;
}

__global__ __launch_bounds__(256) void scatter_kernel(
    const int* __restrict__ row, const int* __restrict__ col,
    const float* __restrict__ val, int* __restrict__ woff,
    int* __restrict__ scol, float* __restrict__ sval, int e) {
  int i = blockIdx.x * 256 + threadIdx.x;
  if (i >= e) return;
  int r = row[i];
  int p = atomicAdd(&woff[r], 1);
  scol[p] = col[i];
  sval[p] = val[i];
}

// ---------------- CSR SpMM ----------------

__global__ __launch_bounds__(256) void spmm_csr_128(
    const int* __restrict__ rowptr, const int* __restrict__ scol,
    const float* __restrict__ sval, const float* __restrict__ h,
    float* __restrict__ OA, float* __restrict__ OB, int n) {
  int tid = threadIdx.x;
  int r = blockIdx.x * 8 + (tid >> 5);
  if (r >= n) return;
  int lane = tid & 31;
  int lo = rowptr[r], hi = rowptr[r + 1];
  const float4* h4 = (const float4*)h;
  float4 acc = make_float4(0.f, 0.f, 0.f, 0.f);
  for (int e = lo; e < hi; ++e) {
    float v = sval[e];
    int c = scol[e];
    float4 hv = h4[(long)c * 32 + lane];
    acc.x += v * hv.x;
    acc.y += v * hv.y;
    acc.z += v * hv.z;
    acc.w += v * hv.w;
  }
  if (lane < 16)
    ((float4*)OA)[(long)r * 16 + lane] = acc;
  else
    ((float4*)OB)[(long)r * 16 + (lane - 16)] = acc;
}

__global__ __launch_bounds__(256) void spmm_csr_64(
    const int* __restrict__ rowptr, const int* __restrict__ scol,
    const float* __restrict__ sval, const float* __restrict__ h,
    const float* __restrict__ b2, float* __restrict__ out, int n) {
  int tid = threadIdx.x;
  int r = blockIdx.x * 16 + (tid >> 4);
  if (r >= n) return;
  int lane = tid & 15;
  float4 acc = ((const float4*)b2)[lane];
  int lo = rowptr[r], hi = rowptr[r + 1];
  const float4* h4 = (const float4*)h;
  for (int e = lo; e < hi; ++e) {
    float v = sval[e];
    int c = scol[e];
    float4 hv = h4[(long)c * 16 + lane];
    acc.x += v * hv.x;
    acc.y += v * hv.y;
    acc.z += v * hv.z;
    acc.w += v * hv.w;
  }
  ((float4*)out)[(long)r * 16 + lane] = acc;
}

// H[n][64] = relu(S + b1) @ W2[128][64]; S given as two n*64 halves.
__global__ __launch_bounds__(256) void gemm_relu_128x64(
    const float* __restrict__ SA, const float* __restrict__ SB,
    const float* __restrict__ B1, const float* __restrict__ W2,
    float* __restrict__ H, int nrows) {
  __shared__ __attribute__((aligned(16))) float ws[128 * 64];
  __shared__ __attribute__((aligned(16))) float xs[32 * 128];
  int tid = threadIdx.x;
  const float4* W4 = (const float4*)W2;
  float4* ws4 = (float4*)ws;
#pragma unroll
  for (int i = 0; i < 8; ++i) ws4[i * 256 + tid] = W4[i * 256 + tid];

  long row0 = (long)blockIdx.x * 32;
  const float4* SA4 = (const float4*)SA;
  const float4* SB4 = (const float4*)SB;
  float4* xs4 = (float4*)xs;
#pragma unroll
  for (int i = 0; i < 4; ++i) {
    int flat = i * 256 + tid;
    int rl = flat >> 5, f4 = flat & 31;
    long rr = row0 + rl;
    float4 sv = make_float4(0.f, 0.f, 0.f, 0.f);
    if (rr < nrows)
      sv = (f4 < 16) ? SA4[rr * 16 + f4] : SB4[rr * 16 + (f4 - 16)];
    float4 bv = ((const float4*)B1)[f4];
    sv.x = fmaxf(sv.x + bv.x, 0.f);
    sv.y = fmaxf(sv.y + bv.y, 0.f);
    sv.z = fmaxf(sv.z + bv.z, 0.f);
    sv.w = fmaxf(sv.w + bv.w, 0.f);
    xs4[flat] = sv;
  }
  __syncthreads();

  int c = tid & 63;
  int wv = tid >> 6;
  const float* xrow = xs + wv * 8 * 128;
  float acc[8] = {};
#pragma unroll 4
  for (int k4 = 0; k4 < 32; ++k4) {
    float wk[4];
#pragma unroll
    for (int j = 0; j < 4; ++j) wk[j] = ws[(k4 * 4 + j) * 64 + c];
#pragma unroll
    for (int r = 0; r < 8; ++r) {
      float4 xv = *(const float4*)(xrow + r * 128 + k4 * 4);
      acc[r] += xv.x * wk[0] + xv.y * wk[1] + xv.z * wk[2] + xv.w * wk[3];
    }
  }
#pragma unroll
  for (int r = 0; r < 8; ++r) {
    long rr = row0 + wv * 8 + r;
    if (rr < nrows) H[rr * 64 + c] = acc[r];
  }
}

// ---------------- final fuse (16 lanes per node) ----------------
__global__ __launch_bounds__(256) void final_fuse(
    const float* __restrict__ emb1, const float* __restrict__ emb2,
    const float* __restrict__ com1, const float* __restrict__ com2,
    const float* __restrict__ attw1, const float* __restrict__ attb1,
    const float* __restrict__ attw2, const float* __restrict__ mlpw,
    const float* __restrict__ mlpb, float* __restrict__ out_logp,
    float* __restrict__ out_beta, float* __restrict__ out_emb, int n) {
  __shared__ __attribute__((aligned(16))) float w1t[16][64];
  __shared__ __attribute__((aligned(16))) float mwt[8][64];
  __shared__ float b1s[16];
  __shared__ float w2s[16];
  __shared__ float mbs[8];
  int tid = threadIdx.x;
  for (int idx = tid; idx < 1024; idx += 256)
    w1t[idx & 15][idx >> 4] = attw1[idx];
  for (int idx = tid; idx < 512; idx += 256)
    mwt[idx & 7][idx >> 3] = mlpw[idx];
  if (tid < 16) {
    b1s[tid] = attb1[tid];
    w2s[tid] = attw2[tid];
  }
  if (tid < 8) mbs[tid] = mlpb[tid];
  __syncthreads();

  int lane = tid & 15;
  long i = ((long)blockIdx.x * 256 + tid) >> 4;
  bool alive = i < n;
  long ii = alive ? i : (long)(n - 1);

  float4 z0 = ((const float4*)emb1)[ii * 16 + lane];
  float4 z1 = ((const float4*)emb2)[ii * 16 + lane];
  float4 x1 = ((const float4*)com1)[ii * 16 + lane];
  float4 x2 = ((const float4*)com2)[ii * 16 + lane];
  float4 z2 = make_float4(0.5f * (x1.x + x2.x), 0.5f * (x1.y + x2.y),
                          0.5f * (x1.z + x2.z), 0.5f * (x1.w + x2.w));

  float a0[16], a1[16], a2[16];
#pragma unroll
  for (int m = 0; m < 16; ++m) {
    float4 w = *(const float4*)&w1t[m][lane * 4];
    a0[m] = z0.x * w.x + z0.y * w.y + z0.z * w.z + z0.w * w.w;
    a1[m] = z1.x * w.x + z1.y * w.y + z1.z * w.z + z1.w * w.w;
    a2[m] = z2.x * w.x + z2.y * w.y + z2.z * w.z + z2.w * w.w;
  }
#pragma unroll
  for (int d = 1; d < 16; d <<= 1) {
#pragma unroll
    for (int m = 0; m < 16; ++m) {
      a0[m] += __shfl_xor(a0[m], d);
      a1[m] += __shfl_xor(a1[m], d);
      a2[m] += __shfl_xor(a2[m], d);
    }
  }
  float sc0 = 0.f, sc1 = 0.f, sc2 = 0.f;
#pragma unroll
  for (int m = 0; m < 16; ++m) {
    float wm = w2s[m], bm = b1s[m];
    sc0 += tanhf(a0[m] + bm) * wm;
    sc1 += tanhf(a1[m] + bm) * wm;
    sc2 += tanhf(a2[m] + bm) * wm;
  }
  float mx = fmaxf(sc0, fmaxf(sc1, sc2));
  float ex0 = expf(sc0 - mx), ex1 = expf(sc1 - mx), ex2 = expf(sc2 - mx);
  float inv = 1.f / (ex0 + ex1 + ex2);
  float be0 = ex0 * inv, be1 = ex1 * inv, be2 = ex2 * inv;

  float4 em;
  em.x = be0 * z0.x + be1 * z1.x + be2 * z2.x;
  em.y = be0 * z0.y + be1 * z1.y + be2 * z2.y;
  em.z = be0 * z0.z + be1 * z1.z + be2 * z2.z;
  em.w = be0 * z0.w + be1 * z1.w + be2 * z2.w;
  if (alive) ((float4*)out_emb)[i * 16 + lane] = em;

  float lg[8];
#pragma unroll
  for (int p = 0; p < 8; ++p) {
    float4 w = *(const float4*)&mwt[p][lane * 4];
    lg[p] = em.x * w.x + em.y * w.y + em.z * w.z + em.w * w.w;
  }
#pragma unroll
  for (int d = 1; d < 16; d <<= 1) {
#pragma unroll
    for (int p = 0; p < 8; ++p) lg[p] += __shfl_xor(lg[p], d);
  }
#pragma unroll
  for (int p = 0; p < 8; ++p) lg[p] += mbs[p];
  float m2 = lg[0];
#pragma unroll
  for (int p = 1; p < 8; ++p) m2 = fmaxf(m2, lg[p]);
  float ssum = 0.f;
#pragma unroll
  for (int p = 0; p < 8; ++p) ssum += expf(lg[p] - m2);
  float ls = m2 + logf(ssum);

  if (alive && lane == 0) {
    float4 o0 = make_float4(lg[0] - ls, lg[1] - ls, lg[2] - ls, lg[3] - ls);
    float4 o1 = make_float4(lg[4] - ls, lg[5] - ls, lg[6] - ls, lg[7] - ls);
    *(float4*)&out_logp[i * 8] = o0;
    *(float4*)&out_logp[i * 8 + 4] = o1;
    out_beta[i * 3 + 0] = be0;
    out_beta[i * 3 + 1] = be1;
    out_beta[i * 3 + 2] = be2;
  }
}

extern "C" void kernel_launch(void* const* d_in, const int* in_sizes, int n_in,
                              void* d_out, int out_size, void* d_ws,
                              size_t ws_size, hipStream_t stream) {
  const float* x = (const float*)d_in[0];
  const int* srow = (const int*)d_in[1];
  const int* scol_in = (const int*)d_in[2];
  const float* sval_in = (const float*)d_in[3];
  const int* frow = (const int*)d_in[4];
  const int* fcol_in = (const int*)d_in[5];
  const float* fval_in = (const float*)d_in[6];
  const float* w_s1_1 = (const float*)d_in[7];
  const float* b_s1_1 = (const float*)d_in[8];
  const float* w_s1_2 = (const float*)d_in[9];
  const float* b_s1_2 = (const float*)d_in[10];
  const float* w_s2_1 = (const float*)d_in[11];
  const float* b_s2_1 = (const float*)d_in[12];
  const float* w_s2_2 = (const float*)d_in[13];
  const float* b_s2_2 = (const float*)d_in[14];
  const float* w_c_1 = (const float*)d_in[15];
  const float* b_c_1 = (const float*)d_in[16];
  const float* w_c_2 = (const float*)d_in[17];
  const float* b_c_2 = (const float*)d_in[18];
  const float* attw1 = (const float*)d_in[19];
  const float* attb1 = (const float*)d_in[20];
  const float* attw2 = (const float*)d_in[21];
  const float* mlpw = (const float*)d_in[22];
  const float* mlpb = (const float*)d_in[23];

  const int n = in_sizes[0] / 128;  // 100000
  const int e = in_sizes[1];        // 1600000

  float* out = (float*)d_out;
  float* o_logp = out;
  float* o_beta = out + (size_t)n * 8;
  float* o_emb1 = out + (size_t)n * 11;
  float* o_com1 = o_emb1 + (size_t)n * 64;
  float* o_com2 = o_com1 + (size_t)n * 64;
  float* o_emb2 = o_com2 + (size_t)n * 64;
  float* o_emb = o_emb2 + (size_t)n * 64;

  // workspace layout
  float* xw = (float*)d_ws;                       // n*128 floats
  int* cnt = (int*)(xw + (size_t)n * 128);        // n
  int* rowptr = cnt + n;                          // n+1
  int* woff = rowptr + n + 1;                     // n
  int* part = woff + n;                           // ceil(n/1024) (<=256)
  int* g_col = part + 256;                        // e
  float* g_val = (float*)(g_col + e);             // e
  float* sB_ws = g_val + e;                       // n*64 spare region

  float* hw = o_emb;  // final_fuse overwrites at the end

  const int gemmBlocks = (n + 31) / 32;
  const int histBlocks = (e + 255) / 256;
  const int scanBlocks = (n + 1023) / 1024;  // 98
  const int spmm128Blocks = (n + 7) / 8;
  const int spmm64Blocks = (n + 15) / 16;

  auto build_csr = [&](const int* r, const int* c, const float* v) {
    hipMemsetAsync(cnt, 0, (size_t)n * sizeof(int), stream);
    hist_kernel<<<histBlocks, 256, 0, stream>>>(r, cnt, e);
    scan_partial<<<scanBlocks, 256, 0, stream>>>(cnt, part, n);
    scan_tops<<<1, 256, 0, stream>>>(part, scanBlocks);
    scan_final<<<scanBlocks, 256, 0, stream>>>(cnt, part, rowptr, woff, n, e);
    scatter_kernel<<<histBlocks, 256, 0, stream>>>(r, c, v, woff, g_col,
                                                   g_val, e);
  };

  auto gcn_tail = [&](const float* w1, const float* bb1, const float* w2,
                      const float* bb2, float* dest, float* sA, float* sB) {
    gemm_128x128<<<gemmBlocks, 256, 0, stream>>>(x, w1, xw, n);
    spmm_csr_128<<<spmm128Blocks, 256, 0, stream>>>(rowptr, g_col, g_val, xw,
                                                    sA, sB, n);
    gemm_relu_128x64<<<gemmBlocks, 256, 0, stream>>>(sA, sB, bb1, w2, hw, n);
    spmm_csr_64<<<spmm64Blocks, 256, 0, stream>>>(rowptr, g_col, g_val, hw,
                                                  bb2, dest, n);
  };

  // graph sadj: emb1 (w_s1), com1 (w_c)
  build_csr(srow, scol_in, sval_in);
  gcn_tail(w_s1_1, b_s1_1, w_s1_2, b_s1_2, o_emb1, o_com1, o_com2);
  gcn_tail(w_c_1, b_c_1, w_c_2, b_c_2, o_com1, o_com2, o_emb2);

  // graph fadj: com2 (w_c), emb2 (w_s2)
  build_csr(frow, fcol_in, fval_in);
  gcn_tail(w_c_1, b_c_1, w_c_2, b_c_2, o_com2, o_emb2, sB_ws);
  gcn_tail(w_s2_1, b_s2_1, w_s2_2, b_s2_2, o_emb2, o_emb2, sB_ws);

  final_fuse<<<(int)(((long)n * 16 + 255) / 256), 256, 0, stream>>>(
      o_emb1, o_emb2, o_com1, o_com2, attw1, attb1, attw2, mlpw, mlpb, o_logp,
      o_beta, o_emb, n);
}

// Round 5
// 1682.196 us; speedup vs baseline: 10.7580x; 1.3228x over previous
//
#include <hip/hip_runtime.h>

// ---------------------------------------------------------------------------
// SFGCN forward on MI355X, round 5:
//  - gemm_128x128 v2: X tile in LDS (coalesced), W k-split into 2x32KB phases
//    -> 48KB LDS, 3 blocks/CU (was 64KB/2 blocks, latency-bound at 27% VALU).
//  - reorder tails so x@w_c_1 is computed ONCE (com2 reuses xw across graphs).
// ---------------------------------------------------------------------------

// C[n][128] = X[n][128] @ W[128][128].
// LDS: xs 16KB (X tile, 32 rows) + ws 32KB (W k-half) = 48KB -> 3 blocks/CU.
__global__ __launch_bounds__(256) void gemm_128x128(
    const float* __restrict__ X, const float* __restrict__ W,
    float* __restrict__ C, int nrows) {
  __shared__ __attribute__((aligned(16))) float ws[64 * 128];
  __shared__ __attribute__((aligned(16))) float xs[32 * 128];
  int tid = threadIdx.x;
  long row0 = (long)blockIdx.x * 32;

  // stage X tile (coalesced): 32 rows x 128 f32 = 1024 float4
  const float4* X4 = (const float4*)X;
  float4* xs4 = (float4*)xs;
  long lim4 = (long)nrows * 32;
#pragma unroll
  for (int i = 0; i < 4; ++i) {
    long idx4 = row0 * 32 + i * 256 + tid;
    xs4[i * 256 + tid] =
        (idx4 < lim4) ? X4[idx4] : make_float4(0.f, 0.f, 0.f, 0.f);
  }

  int c0 = tid & 63;
  int wv = tid >> 6;
  const float* xrow = xs + wv * 8 * 128;
  float acc0[8] = {}, acc1[8] = {};

  const float4* W4 = (const float4*)W;
  float4* ws4 = (float4*)ws;
#pragma unroll
  for (int ph = 0; ph < 2; ++ph) {
    if (ph) __syncthreads();  // WAR: all waves done with previous W half
    // stage W rows [64*ph, 64*ph+64): 2048 float4, 8 per thread
#pragma unroll
    for (int i = 0; i < 8; ++i)
      ws4[i * 256 + tid] = W4[ph * 2048 + i * 256 + tid];
    __syncthreads();  // (ph==0 also covers xs)
#pragma unroll 4
    for (int k4 = 0; k4 < 16; ++k4) {
      float wa[4], wb[4];
#pragma unroll
      for (int j = 0; j < 4; ++j) {
        wa[j] = ws[(k4 * 4 + j) * 128 + c0];
        wb[j] = ws[(k4 * 4 + j) * 128 + c0 + 64];
      }
#pragma unroll
      for (int r = 0; r < 8; ++r) {
        float4 xv = *(const float4*)(xrow + r * 128 + ph * 64 + k4 * 4);
        acc0[r] += xv.x * wa[0] + xv.y * wa[1] + xv.z * wa[2] + xv.w * wa[3];
        acc1[r] += xv.x * wb[0] + xv.y * wb[1] + xv.z * wb[2] + xv.w * wb[3];
      }
    }
  }
#pragma unroll
  for (int r = 0; r < 8; ++r) {
    long rr = row0 + wv * 8 + r;
    if (rr < nrows) {
      C[rr * 128 + c0] = acc0[r];
      C[rr * 128 + c0 + 64] = acc1[r];
    }
  }
}

// ---------------- CSR build ----------------

__global__ __launch_bounds__(256) void hist_kernel(
    const int* __restrict__ row, int* __restrict__ cnt, int e) {
  int i = blockIdx.x * 256 + threadIdx.x;
  if (i < e) atomicAdd(&cnt[row[i]], 1);
}

__global__ __launch_bounds__(256) void scan_partial(
    const int* __restrict__ cnt, int* __restrict__ part, int n) {
  __shared__ int red[256];
  int t = threadIdx.x;
  int base = blockIdx.x * 1024 + t * 4;
  int s = 0;
#pragma unroll
  for (int j = 0; j < 4; ++j) {
    int idx = base + j;
    if (idx < n) s += cnt[idx];
  }
  red[t] = s;
  __syncthreads();
#pragma unroll
  for (int d = 128; d > 0; d >>= 1) {
    if (t < d) red[t] += red[t + d];
    __syncthreads();
  }
  if (t == 0) part[blockIdx.x] = red[0];
}

__global__ __launch_bounds__(256) void scan_tops(int* __restrict__ part,
                                                 int nb) {
  __shared__ int lds[256];
  int t = threadIdx.x;
  lds[t] = (t < nb) ? part[t] : 0;
  __syncthreads();
#pragma unroll
  for (int d = 1; d < 256; d <<= 1) {
    int v = (t >= d) ? lds[t - d] : 0;
    __syncthreads();
    lds[t] += v;
    __syncthreads();
  }
  if (t < nb) part[t] = (t == 0) ? 0 : lds[t - 1];
}

__global__ __launch_bounds__(256) void scan_final(
    const int* __restrict__ cnt, const int* __restrict__ part,
    int* __restrict__ rowptr, int* __restrict__ woff, int n, int e) {
  __shared__ int lds[256];
  int t = threadIdx.x;
  int base = blockIdx.x * 1024 + t * 4;
  int c[4];
  int s = 0;
#pragma unroll
  for (int j = 0; j < 4; ++j) {
    int idx = base + j;
    c[j] = (idx < n) ? cnt[idx] : 0;
    s += c[j];
  }
  lds[t] = s;
  __syncthreads();
#pragma unroll
  for (int d = 1; d < 256; d <<= 1) {
    int v = (t >= d) ? lds[t - d] : 0;
    __syncthreads();
    lds[t] += v;
    __syncthreads();
  }
  int off = part[blockIdx.x] + ((t == 0) ? 0 : lds[t - 1]);
#pragma unroll
  for (int j = 0; j < 4; ++j) {
    int idx = base + j;
    if (idx < n) {
      rowptr[idx] = off;
      woff[idx] = off;
      off += c[j];
    }
  }
  if (blockIdx.x == 0 && t == 0) rowptr[n] = e;
}

__global__ __launch_bounds__(256) void scatter_kernel(
    const int* __restrict__ row, const int* __restrict__ col,
    const float* __restrict__ val, int* __restrict__ woff,
    int* __restrict__ scol, float* __restrict__ sval, int e) {
  int i = blockIdx.x * 256 + threadIdx.x;
  if (i >= e) return;
  int r = row[i];
  int p = atomicAdd(&woff[r], 1);
  scol[p] = col[i];
  sval[p] = val[i];
}

// ---------------- CSR SpMM ----------------

__global__ __launch_bounds__(256) void spmm_csr_128(
    const int* __restrict__ rowptr, const int* __restrict__ scol,
    const float* __restrict__ sval, const float* __restrict__ h,
    float* __restrict__ OA, float* __restrict__ OB, int n) {
  int tid = threadIdx.x;
  int r = blockIdx.x * 8 + (tid >> 5);
  if (r >= n) return;
  int lane = tid & 31;
  int lo = rowptr[r], hi = rowptr[r + 1];
  const float4* h4 = (const float4*)h;
  float4 acc = make_float4(0.f, 0.f, 0.f, 0.f);
  for (int e = lo; e < hi; ++e) {
    float v = sval[e];
    int c = scol[e];
    float4 hv = h4[(long)c * 32 + lane];
    acc.x += v * hv.x;
    acc.y += v * hv.y;
    acc.z += v * hv.z;
    acc.w += v * hv.w;
  }
  if (lane < 16)
    ((float4*)OA)[(long)r * 16 + lane] = acc;
  else
    ((float4*)OB)[(long)r * 16 + (lane - 16)] = acc;
}

__global__ __launch_bounds__(256) void spmm_csr_64(
    const int* __restrict__ rowptr, const int* __restrict__ scol,
    const float* __restrict__ sval, const float* __restrict__ h,
    const float* __restrict__ b2, float* __restrict__ out, int n) {
  int tid = threadIdx.x;
  int r = blockIdx.x * 16 + (tid >> 4);
  if (r >= n) return;
  int lane = tid & 15;
  float4 acc = ((const float4*)b2)[lane];
  int lo = rowptr[r], hi = rowptr[r + 1];
  const float4* h4 = (const float4*)h;
  for (int e = lo; e < hi; ++e) {
    float v = sval[e];
    int c = scol[e];
    float4 hv = h4[(long)c * 16 + lane];
    acc.x += v * hv.x;
    acc.y += v * hv.y;
    acc.z += v * hv.z;
    acc.w += v * hv.w;
  }
  ((float4*)out)[(long)r * 16 + lane] = acc;
}

// H[n][64] = relu(S + b1) @ W2[128][64]; S given as two n*64 halves.
__global__ __launch_bounds__(256) void gemm_relu_128x64(
    const float* __restrict__ SA, const float* __restrict__ SB,
    const float* __restrict__ B1, const float* __restrict__ W2,
    float* __restrict__ H, int nrows) {
  __shared__ __attribute__((aligned(16))) float ws[128 * 64];
  __shared__ __attribute__((aligned(16))) float xs[32 * 128];
  int tid = threadIdx.x;
  const float4* W4 = (const float4*)W2;
  float4* ws4 = (float4*)ws;
#pragma unroll
  for (int i = 0; i < 8; ++i) ws4[i * 256 + tid] = W4[i * 256 + tid];

  long row0 = (long)blockIdx.x * 32;
  const float4* SA4 = (const float4*)SA;
  const float4* SB4 = (const float4*)SB;
  float4* xs4 = (float4*)xs;
#pragma unroll
  for (int i = 0; i < 4; ++i) {
    int flat = i * 256 + tid;
    int rl = flat >> 5, f4 = flat & 31;
    long rr = row0 + rl;
    float4 sv = make_float4(0.f, 0.f, 0.f, 0.f);
    if (rr < nrows)
      sv = (f4 < 16) ? SA4[rr * 16 + f4] : SB4[rr * 16 + (f4 - 16)];
    float4 bv = ((const float4*)B1)[f4];
    sv.x = fmaxf(sv.x + bv.x, 0.f);
    sv.y = fmaxf(sv.y + bv.y, 0.f);
    sv.z = fmaxf(sv.z + bv.z, 0.f);
    sv.w = fmaxf(sv.w + bv.w, 0.f);
    xs4[flat] = sv;
  }
  __syncthreads();

  int c = tid & 63;
  int wv = tid >> 6;
  const float* xrow = xs + wv * 8 * 128;
  float acc[8] = {};
#pragma unroll 4
  for (int k4 = 0; k4 < 32; ++k4) {
    float wk[4];
#pragma unroll
    for (int j = 0; j < 4; ++j) wk[j] = ws[(k4 * 4 + j) * 64 + c];
#pragma unroll
    for (int r = 0; r < 8; ++r) {
      float4 xv = *(const float4*)(xrow + r * 128 + k4 * 4);
      acc[r] += xv.x * wk[0] + xv.y * wk[1] + xv.z * wk[2] + xv.w * wk[3];
    }
  }
#pragma unroll
  for (int r = 0; r < 8; ++r) {
    long rr = row0 + wv * 8 + r;
    if (rr < nrows) H[rr * 64 + c] = acc[r];
  }
}

// ---------------- final fuse (16 lanes per node) ----------------
__global__ __launch_bounds__(256) void final_fuse(
    const float* __restrict__ emb1, const float* __restrict__ emb2,
    const float* __restrict__ com1, const float* __restrict__ com2,
    const float* __restrict__ attw1, const float* __restrict__ attb1,
    const float* __restrict__ attw2, const float* __restrict__ mlpw,
    const float* __restrict__ mlpb, float* __restrict__ out_logp,
    float* __restrict__ out_beta, float* __restrict__ out_emb, int n) {
  __shared__ __attribute__((aligned(16))) float w1t[16][64];
  __shared__ __attribute__((aligned(16))) float mwt[8][64];
  __shared__ float b1s[16];
  __shared__ float w2s[16];
  __shared__ float mbs[8];
  int tid = threadIdx.x;
  for (int idx = tid; idx < 1024; idx += 256)
    w1t[idx & 15][idx >> 4] = attw1[idx];
  for (int idx = tid; idx < 512; idx += 256)
    mwt[idx & 7][idx >> 3] = mlpw[idx];
  if (tid < 16) {
    b1s[tid] = attb1[tid];
    w2s[tid] = attw2[tid];
  }
  if (tid < 8) mbs[tid] = mlpb[tid];
  __syncthreads();

  int lane = tid & 15;
  long i = ((long)blockIdx.x * 256 + tid) >> 4;
  bool alive = i < n;
  long ii = alive ? i : (long)(n - 1);

  float4 z0 = ((const float4*)emb1)[ii * 16 + lane];
  float4 z1 = ((const float4*)emb2)[ii * 16 + lane];
  float4 x1 = ((const float4*)com1)[ii * 16 + lane];
  float4 x2 = ((const float4*)com2)[ii * 16 + lane];
  float4 z2 = make_float4(0.5f * (x1.x + x2.x), 0.5f * (x1.y + x2.y),
                          0.5f * (x1.z + x2.z), 0.5f * (x1.w + x2.w));

  float a0[16], a1[16], a2[16];
#pragma unroll
  for (int m = 0; m < 16; ++m) {
    float4 w = *(const float4*)&w1t[m][lane * 4];
    a0[m] = z0.x * w.x + z0.y * w.y + z0.z * w.z + z0.w * w.w;
    a1[m] = z1.x * w.x + z1.y * w.y + z1.z * w.z + z1.w * w.w;
    a2[m] = z2.x * w.x + z2.y * w.y + z2.z * w.z + z2.w * w.w;
  }
#pragma unroll
  for (int d = 1; d < 16; d <<= 1) {
#pragma unroll
    for (int m = 0; m < 16; ++m) {
      a0[m] += __shfl_xor(a0[m], d);
      a1[m] += __shfl_xor(a1[m], d);
      a2[m] += __shfl_xor(a2[m], d);
    }
  }
  float sc0 = 0.f, sc1 = 0.f, sc2 = 0.f;
#pragma unroll
  for (int m = 0; m < 16; ++m) {
    float wm = w2s[m], bm = b1s[m];
    sc0 += tanhf(a0[m] + bm) * wm;
    sc1 += tanhf(a1[m] + bm) * wm;
    sc2 += tanhf(a2[m] + bm) * wm;
  }
  float mx = fmaxf(sc0, fmaxf(sc1, sc2));
  float ex0 = expf(sc0 - mx), ex1 = expf(sc1 - mx), ex2 = expf(sc2 - mx);
  float inv = 1.f / (ex0 + ex1 + ex2);
  float be0 = ex0 * inv, be1 = ex1 * inv, be2 = ex2 * inv;

  float4 em;
  em.x = be0 * z0.x + be1 * z1.x + be2 * z2.x;
  em.y = be0 * z0.y + be1 * z1.y + be2 * z2.y;
  em.z = be0 * z0.z + be1 * z1.z + be2 * z2.z;
  em.w = be0 * z0.w + be1 * z1.w + be2 * z2.w;
  if (alive) ((float4*)out_emb)[i * 16 + lane] = em;

  float lg[8];
#pragma unroll
  for (int p = 0; p < 8; ++p) {
    float4 w = *(const float4*)&mwt[p][lane * 4];
    lg[p] = em.x * w.x + em.y * w.y + em.z * w.z + em.w * w.w;
  }
#pragma unroll
  for (int d = 1; d < 16; d <<= 1) {
#pragma unroll
    for (int p = 0; p < 8; ++p) lg[p] += __shfl_xor(lg[p], d);
  }
#pragma unroll
  for (int p = 0; p < 8; ++p) lg[p] += mbs[p];
  float m2 = lg[0];
#pragma unroll
  for (int p = 1; p < 8; ++p) m2 = fmaxf(m2, lg[p]);
  float ssum = 0.f;
#pragma unroll
  for (int p = 0; p < 8; ++p) ssum += expf(lg[p] - m2);
  float ls = m2 + logf(ssum);

  if (alive && lane == 0) {
    float4 o0 = make_float4(lg[0] - ls, lg[1] - ls, lg[2] - ls, lg[3] - ls);
    float4 o1 = make_float4(lg[4] - ls, lg[5] - ls, lg[6] - ls, lg[7] - ls);
    *(float4*)&out_logp[i * 8] = o0;
    *(float4*)&out_logp[i * 8 + 4] = o1;
    out_beta[i * 3 + 0] = be0;
    out_beta[i * 3 + 1] = be1;
    out_beta[i * 3 + 2] = be2;
  }
}

extern "C" void kernel_launch(void* const* d_in, const int* in_sizes, int n_in,
                              void* d_out, int out_size, void* d_ws,
                              size_t ws_size, hipStream_t stream) {
  const float* x = (const float*)d_in[0];
  const int* srow = (const int*)d_in[1];
  const int* scol_in = (const int*)d_in[2];
  const float* sval_in = (const float*)d_in[3];
  const int* frow = (const int*)d_in[4];
  const int* fcol_in = (const int*)d_in[5];
  const float* fval_in = (const float*)d_in[6];
  const float* w_s1_1 = (const float*)d_in[7];
  const float* b_s1_1 = (const float*)d_in[8];
  const float* w_s1_2 = (const float*)d_in[9];
  const float* b_s1_2 = (const float*)d_in[10];
  const float* w_s2_1 = (const float*)d_in[11];
  const float* b_s2_1 = (const float*)d_in[12];
  const float* w_s2_2 = (const float*)d_in[13];
  const float* b_s2_2 = (const float*)d_in[14];
  const float* w_c_1 = (const float*)d_in[15];
  const float* b_c_1 = (const float*)d_in[16];
  const float* w_c_2 = (const float*)d_in[17];
  const float* b_c_2 = (const float*)d_in[18];
  const float* attw1 = (const float*)d_in[19];
  const float* attb1 = (const float*)d_in[20];
  const float* attw2 = (const float*)d_in[21];
  const float* mlpw = (const float*)d_in[22];
  const float* mlpb = (const float*)d_in[23];

  const int n = in_sizes[0] / 128;  // 100000
  const int e = in_sizes[1];        // 1600000

  float* out = (float*)d_out;
  float* o_logp = out;
  float* o_beta = out + (size_t)n * 8;
  float* o_emb1 = out + (size_t)n * 11;
  float* o_com1 = o_emb1 + (size_t)n * 64;
  float* o_com2 = o_com1 + (size_t)n * 64;
  float* o_emb2 = o_com2 + (size_t)n * 64;
  float* o_emb = o_emb2 + (size_t)n * 64;

  // workspace layout
  float* xw = (float*)d_ws;                       // n*128 floats
  int* cnt = (int*)(xw + (size_t)n * 128);        // n
  int* rowptr = cnt + n;                          // n+1
  int* woff = rowptr + n + 1;                     // n
  int* part = woff + n;                           // <=256
  int* g_col = part + 256;                        // e
  float* g_val = (float*)(g_col + e);             // e
  float* sB_ws = g_val + e;                       // n*64 spare region

  float* hw = o_emb;  // final_fuse overwrites at the end

  const int gemmBlocks = (n + 31) / 32;
  const int histBlocks = (e + 255) / 256;
  const int scanBlocks = (n + 1023) / 1024;
  const int spmm128Blocks = (n + 7) / 8;
  const int spmm64Blocks = (n + 15) / 16;

  auto build_csr = [&](const int* r, const int* c, const float* v) {
    hipMemsetAsync(cnt, 0, (size_t)n * sizeof(int), stream);
    hist_kernel<<<histBlocks, 256, 0, stream>>>(r, cnt, e);
    scan_partial<<<scanBlocks, 256, 0, stream>>>(cnt, part, n);
    scan_tops<<<1, 256, 0, stream>>>(part, scanBlocks);
    scan_final<<<scanBlocks, 256, 0, stream>>>(cnt, part, rowptr, woff, n, e);
    scatter_kernel<<<histBlocks, 256, 0, stream>>>(r, c, v, woff, g_col,
                                                   g_val, e);
  };

  // tail WITHOUT the dense layer-1 gemm (xw assumed current)
  auto gcn_tail = [&](const float* bb1, const float* w2, const float* bb2,
                      float* dest, float* sA, float* sB) {
    spmm_csr_128<<<spmm128Blocks, 256, 0, stream>>>(rowptr, g_col, g_val, xw,
                                                    sA, sB, n);
    gemm_relu_128x64<<<gemmBlocks, 256, 0, stream>>>(sA, sB, bb1, w2, hw, n);
    spmm_csr_64<<<spmm64Blocks, 256, 0, stream>>>(rowptr, g_col, g_val, hw,
                                                  bb2, dest, n);
  };

  // graph sadj: emb1 (w_s1), com1 (w_c)
  build_csr(srow, scol_in, sval_in);
  gemm_128x128<<<gemmBlocks, 256, 0, stream>>>(x, w_s1_1, xw, n);
  gcn_tail(b_s1_1, w_s1_2, b_s1_2, o_emb1, o_com1, o_com2);
  gemm_128x128<<<gemmBlocks, 256, 0, stream>>>(x, w_c_1, xw, n);
  gcn_tail(b_c_1, w_c_2, b_c_2, o_com1, o_com2, o_emb2);

  // graph fadj: com2 reuses xw = x @ w_c_1 (no recompute), then emb2 (w_s2)
  build_csr(frow, fcol_in, fval_in);
  gcn_tail(b_c_1, w_c_2, b_c_2, o_com2, o_emb2, sB_ws);
  gemm_128x128<<<gemmBlocks, 256, 0, stream>>>(x, w_s2_1, xw, n);
  gcn_tail(b_s2_1, w_s2_2, b_s2_2, o_emb2, o_emb2, sB_ws);

  final_fuse<<<(int)(((long)n * 16 + 255) / 256), 256, 0, stream>>>(
      o_emb1, o_emb2, o_com1, o_com2, attw1, attb1, attw2, mlpw, mlpb, o_logp,
      o_beta, o_emb, n);
}

// Round 6
// 1475.980 us; speedup vs baseline: 12.2611x; 1.1397x over previous
//
#include <hip/hip_runtime.h>

// ---------------------------------------------------------------------------
// SFGCN forward on MI355X, round 6:
//  - ALGEBRAIC REORDER: spmm(adj, x@W1) == (adj@x)@W1. adj@x is weight-
//    independent -> computed ONCE per graph and shared by both tails.
//    128-feat SpMM count: 4 -> 2.
//  - FUSED dense chain: hw = relu(ax@W1 + b1)@W2 in ONE kernel (no n*128
//    intermediate ever touches HBM). 48KB LDS -> 3 blocks/CU.
// Pipeline per graph: build CSR; ax = spmm128(x); per tail: fused_l1l2 ->
// spmm64(+b2). Then fused attention epilogue.
// ---------------------------------------------------------------------------

// ---------------- CSR build ----------------

__global__ __launch_bounds__(256) void hist_kernel(
    const int* __restrict__ row, int* __restrict__ cnt, int e) {
  int i = blockIdx.x * 256 + threadIdx.x;
  if (i < e) atomicAdd(&cnt[row[i]], 1);
}

__global__ __launch_bounds__(256) void scan_partial(
    const int* __restrict__ cnt, int* __restrict__ part, int n) {
  __shared__ int red[256];
  int t = threadIdx.x;
  int base = blockIdx.x * 1024 + t * 4;
  int s = 0;
#pragma unroll
  for (int j = 0; j < 4; ++j) {
    int idx = base + j;
    if (idx < n) s += cnt[idx];
  }
  red[t] = s;
  __syncthreads();
#pragma unroll
  for (int d = 128; d > 0; d >>= 1) {
    if (t < d) red[t] += red[t + d];
    __syncthreads();
  }
  if (t == 0) part[blockIdx.x] = red[0];
}

__global__ __launch_bounds__(256) void scan_tops(int* __restrict__ part,
                                                 int nb) {
  __shared__ int lds[256];
  int t = threadIdx.x;
  lds[t] = (t < nb) ? part[t] : 0;
  __syncthreads();
#pragma unroll
  for (int d = 1; d < 256; d <<= 1) {
    int v = (t >= d) ? lds[t - d] : 0;
    __syncthreads();
    lds[t] += v;
    __syncthreads();
  }
  if (t < nb) part[t] = (t == 0) ? 0 : lds[t - 1];
}

__global__ __launch_bounds__(256) void scan_final(
    const int* __restrict__ cnt, const int* __restrict__ part,
    int* __restrict__ rowptr, int* __restrict__ woff, int n, int e) {
  __shared__ int lds[256];
  int t = threadIdx.x;
  int base = blockIdx.x * 1024 + t * 4;
  int c[4];
  int s = 0;
#pragma unroll
  for (int j = 0; j < 4; ++j) {
    int idx = base + j;
    c[j] = (idx < n) ? cnt[idx] : 0;
    s += c[j];
  }
  lds[t] = s;
  __syncthreads();
#pragma unroll
  for (int d = 1; d < 256; d <<= 1) {
    int v = (t >= d) ? lds[t - d] : 0;
    __syncthreads();
    lds[t] += v;
    __syncthreads();
  }
  int off = part[blockIdx.x] + ((t == 0) ? 0 : lds[t - 1]);
#pragma unroll
  for (int j = 0; j < 4; ++j) {
    int idx = base + j;
    if (idx < n) {
      rowptr[idx] = off;
      woff[idx] = off;
      off += c[j];
    }
  }
  if (blockIdx.x == 0 && t == 0) rowptr[n] = e;
}

__global__ __launch_bounds__(256) void scatter_kernel(
    const int* __restrict__ row, const int* __restrict__ col,
    const float* __restrict__ val, int* __restrict__ woff,
    int* __restrict__ scol, float* __restrict__ sval, int e) {
  int i = blockIdx.x * 256 + threadIdx.x;
  if (i >= e) return;
  int r = row[i];
  int p = atomicAdd(&woff[r], 1);
  scol[p] = col[i];
  sval[p] = val[i];
}

// ---------------- CSR SpMM ----------------

// 128 feats: 32 lanes/row; output split into two n*64 halves OA/OB.
__global__ __launch_bounds__(256) void spmm_csr_128(
    const int* __restrict__ rowptr, const int* __restrict__ scol,
    const float* __restrict__ sval, const float* __restrict__ h,
    float* __restrict__ OA, float* __restrict__ OB, int n) {
  int tid = threadIdx.x;
  int r = blockIdx.x * 8 + (tid >> 5);
  if (r >= n) return;
  int lane = tid & 31;
  int lo = rowptr[r], hi = rowptr[r + 1];
  const float4* h4 = (const float4*)h;
  float4 acc = make_float4(0.f, 0.f, 0.f, 0.f);
  for (int e = lo; e < hi; ++e) {
    float v = sval[e];
    int c = scol[e];
    float4 hv = h4[(long)c * 32 + lane];
    acc.x += v * hv.x;
    acc.y += v * hv.y;
    acc.z += v * hv.z;
    acc.w += v * hv.w;
  }
  if (lane < 16)
    ((float4*)OA)[(long)r * 16 + lane] = acc;
  else
    ((float4*)OB)[(long)r * 16 + (lane - 16)] = acc;
}

// 64 feats: 16 lanes/row, bias as accumulator init.
__global__ __launch_bounds__(256) void spmm_csr_64(
    const int* __restrict__ rowptr, const int* __restrict__ scol,
    const float* __restrict__ sval, const float* __restrict__ h,
    const float* __restrict__ b2, float* __restrict__ out, int n) {
  int tid = threadIdx.x;
  int r = blockIdx.x * 16 + (tid >> 4);
  if (r >= n) return;
  int lane = tid & 15;
  float4 acc = ((const float4*)b2)[lane];
  int lo = rowptr[r], hi = rowptr[r + 1];
  const float4* h4 = (const float4*)h;
  for (int e = lo; e < hi; ++e) {
    float v = sval[e];
    int c = scol[e];
    float4 hv = h4[(long)c * 16 + lane];
    acc.x += v * hv.x;
    acc.y += v * hv.y;
    acc.z += v * hv.z;
    acc.w += v * hv.w;
  }
  ((float4*)out)[(long)r * 16 + lane] = acc;
}

// ---------------- fused dense chain ----------------
// H[n][64] = relu(Ax@W1 + b1) @ W2, Ax given as halves AxA/AxB (n*64 each).
// LDS: xs 16KB (Ax tile; reused for relu'd s) + ws 32KB (W1 k-half / W2).
// 48KB -> 3 blocks/CU.
__global__ __launch_bounds__(256) void fused_l1l2(
    const float* __restrict__ AxA, const float* __restrict__ AxB,
    const float* __restrict__ W1, const float* __restrict__ B1,
    const float* __restrict__ W2, float* __restrict__ H, int nrows) {
  __shared__ __attribute__((aligned(16))) float xs[32 * 128];
  __shared__ __attribute__((aligned(16))) float ws[64 * 128];
  int tid = threadIdx.x;
  long row0 = (long)blockIdx.x * 32;

  // stage Ax tile (coalesced) from the two halves
  const float4* A4 = (const float4*)AxA;
  const float4* B4 = (const float4*)AxB;
  float4* xs4 = (float4*)xs;
#pragma unroll
  for (int i = 0; i < 4; ++i) {
    int flat = i * 256 + tid;  // 32 rows x 32 float4
    int rl = flat >> 5, f4 = flat & 31;
    long rr = row0 + rl;
    float4 sv = make_float4(0.f, 0.f, 0.f, 0.f);
    if (rr < nrows)
      sv = (f4 < 16) ? A4[rr * 16 + f4] : B4[rr * 16 + (f4 - 16)];
    xs4[flat] = sv;
  }

  int c0 = tid & 63;
  int wv = tid >> 6;
  const float* xrow = xs + wv * 8 * 128;  // this wave's private 8 rows
  float acc0[8] = {}, acc1[8] = {};

  // ---- GEMM 1: s = Ax @ W1 (k split in two 64-row phases of W1) ----
  const float4* W14 = (const float4*)W1;
  float4* ws4 = (float4*)ws;
#pragma unroll
  for (int ph = 0; ph < 2; ++ph) {
    if (ph) __syncthreads();  // WAR on ws
#pragma unroll
    for (int i = 0; i < 8; ++i)
      ws4[i * 256 + tid] = W14[ph * 2048 + i * 256 + tid];
    __syncthreads();  // ph==0 also covers xs staging
#pragma unroll 4
    for (int k4 = 0; k4 < 16; ++k4) {
      float wa[4], wb[4];
#pragma unroll
      for (int j = 0; j < 4; ++j) {
        wa[j] = ws[(k4 * 4 + j) * 128 + c0];
        wb[j] = ws[(k4 * 4 + j) * 128 + c0 + 64];
      }
#pragma unroll
      for (int r = 0; r < 8; ++r) {
        float4 xv = *(const float4*)(xrow + r * 128 + ph * 64 + k4 * 4);
        acc0[r] += xv.x * wa[0] + xv.y * wa[1] + xv.z * wa[2] + xv.w * wa[3];
        acc1[r] += xv.x * wb[0] + xv.y * wb[1] + xv.z * wb[2] + xv.w * wb[3];
      }
    }
  }

  // ---- relu(s + b1) written back into xs (own rows only) ----
  float b1a = B1[c0], b1b = B1[c0 + 64];
  __syncthreads();  // all waves done reading ws (and xs phase-1)
#pragma unroll
  for (int r = 0; r < 8; ++r) {
    xs[(wv * 8 + r) * 128 + c0] = fmaxf(acc0[r] + b1a, 0.f);
    xs[(wv * 8 + r) * 128 + c0 + 64] = fmaxf(acc1[r] + b1b, 0.f);
  }

  // ---- stage W2 (128x64 = 32KB) into ws ----
  const float4* W24 = (const float4*)W2;
#pragma unroll
  for (int i = 0; i < 8; ++i) ws4[i * 256 + tid] = W24[i * 256 + tid];
  __syncthreads();

  // ---- GEMM 2: hw = h @ W2 ----
  float acc2[8] = {};
#pragma unroll 4
  for (int k4 = 0; k4 < 32; ++k4) {
    float wk[4];
#pragma unroll
    for (int j = 0; j < 4; ++j) wk[j] = ws[(k4 * 4 + j) * 64 + c0];
#pragma unroll
    for (int r = 0; r < 8; ++r) {
      float4 xv = *(const float4*)(xrow + r * 128 + k4 * 4);
      acc2[r] += xv.x * wk[0] + xv.y * wk[1] + xv.z * wk[2] + xv.w * wk[3];
    }
  }
#pragma unroll
  for (int r = 0; r < 8; ++r) {
    long rr = row0 + wv * 8 + r;
    if (rr < nrows) H[rr * 64 + c0] = acc2[r];
  }
}

// ---------------- final fuse (16 lanes per node) ----------------
__global__ __launch_bounds__(256) void final_fuse(
    const float* __restrict__ emb1, const float* __restrict__ emb2,
    const float* __restrict__ com1, const float* __restrict__ com2,
    const float* __restrict__ attw1, const float* __restrict__ attb1,
    const float* __restrict__ attw2, const float* __restrict__ mlpw,
    const float* __restrict__ mlpb, float* __restrict__ out_logp,
    float* __restrict__ out_beta, float* __restrict__ out_emb, int n) {
  __shared__ __attribute__((aligned(16))) float w1t[16][64];
  __shared__ __attribute__((aligned(16))) float mwt[8][64];
  __shared__ float b1s[16];
  __shared__ float w2s[16];
  __shared__ float mbs[8];
  int tid = threadIdx.x;
  for (int idx = tid; idx < 1024; idx += 256)
    w1t[idx & 15][idx >> 4] = attw1[idx];
  for (int idx = tid; idx < 512; idx += 256)
    mwt[idx & 7][idx >> 3] = mlpw[idx];
  if (tid < 16) {
    b1s[tid] = attb1[tid];
    w2s[tid] = attw2[tid];
  }
  if (tid < 8) mbs[tid] = mlpb[tid];
  __syncthreads();

  int lane = tid & 15;
  long i = ((long)blockIdx.x * 256 + tid) >> 4;
  bool alive = i < n;
  long ii = alive ? i : (long)(n - 1);

  float4 z0 = ((const float4*)emb1)[ii * 16 + lane];
  float4 z1 = ((const float4*)emb2)[ii * 16 + lane];
  float4 x1 = ((const float4*)com1)[ii * 16 + lane];
  float4 x2 = ((const float4*)com2)[ii * 16 + lane];
  float4 z2 = make_float4(0.5f * (x1.x + x2.x), 0.5f * (x1.y + x2.y),
                          0.5f * (x1.z + x2.z), 0.5f * (x1.w + x2.w));

  float a0[16], a1[16], a2[16];
#pragma unroll
  for (int m = 0; m < 16; ++m) {
    float4 w = *(const float4*)&w1t[m][lane * 4];
    a0[m] = z0.x * w.x + z0.y * w.y + z0.z * w.z + z0.w * w.w;
    a1[m] = z1.x * w.x + z1.y * w.y + z1.z * w.z + z1.w * w.w;
    a2[m] = z2.x * w.x + z2.y * w.y + z2.z * w.z + z2.w * w.w;
  }
#pragma unroll
  for (int d = 1; d < 16; d <<= 1) {
#pragma unroll
    for (int m = 0; m < 16; ++m) {
      a0[m] += __shfl_xor(a0[m], d);
      a1[m] += __shfl_xor(a1[m], d);
      a2[m] += __shfl_xor(a2[m], d);
    }
  }
  float sc0 = 0.f, sc1 = 0.f, sc2 = 0.f;
#pragma unroll
  for (int m = 0; m < 16; ++m) {
    float wm = w2s[m], bm = b1s[m];
    sc0 += tanhf(a0[m] + bm) * wm;
    sc1 += tanhf(a1[m] + bm) * wm;
    sc2 += tanhf(a2[m] + bm) * wm;
  }
  float mx = fmaxf(sc0, fmaxf(sc1, sc2));
  float ex0 = expf(sc0 - mx), ex1 = expf(sc1 - mx), ex2 = expf(sc2 - mx);
  float inv = 1.f / (ex0 + ex1 + ex2);
  float be0 = ex0 * inv, be1 = ex1 * inv, be2 = ex2 * inv;

  float4 em;
  em.x = be0 * z0.x + be1 * z1.x + be2 * z2.x;
  em.y = be0 * z0.y + be1 * z1.y + be2 * z2.y;
  em.z = be0 * z0.z + be1 * z1.z + be2 * z2.z;
  em.w = be0 * z0.w + be1 * z1.w + be2 * z2.w;
  if (alive) ((float4*)out_emb)[i * 16 + lane] = em;

  float lg[8];
#pragma unroll
  for (int p = 0; p < 8; ++p) {
    float4 w = *(const float4*)&mwt[p][lane * 4];
    lg[p] = em.x * w.x + em.y * w.y + em.z * w.z + em.w * w.w;
  }
#pragma unroll
  for (int d = 1; d < 16; d <<= 1) {
#pragma unroll
    for (int p = 0; p < 8; ++p) lg[p] += __shfl_xor(lg[p], d);
  }
#pragma unroll
  for (int p = 0; p < 8; ++p) lg[p] += mbs[p];
  float m2 = lg[0];
#pragma unroll
  for (int p = 1; p < 8; ++p) m2 = fmaxf(m2, lg[p]);
  float ssum = 0.f;
#pragma unroll
  for (int p = 0; p < 8; ++p) ssum += expf(lg[p] - m2);
  float ls = m2 + logf(ssum);

  if (alive && lane == 0) {
    float4 o0 = make_float4(lg[0] - ls, lg[1] - ls, lg[2] - ls, lg[3] - ls);
    float4 o1 = make_float4(lg[4] - ls, lg[5] - ls, lg[6] - ls, lg[7] - ls);
    *(float4*)&out_logp[i * 8] = o0;
    *(float4*)&out_logp[i * 8 + 4] = o1;
    out_beta[i * 3 + 0] = be0;
    out_beta[i * 3 + 1] = be1;
    out_beta[i * 3 + 2] = be2;
  }
}

extern "C" void kernel_launch(void* const* d_in, const int* in_sizes, int n_in,
                              void* d_out, int out_size, void* d_ws,
                              size_t ws_size, hipStream_t stream) {
  const float* x = (const float*)d_in[0];
  const int* srow = (const int*)d_in[1];
  const int* scol_in = (const int*)d_in[2];
  const float* sval_in = (const float*)d_in[3];
  const int* frow = (const int*)d_in[4];
  const int* fcol_in = (const int*)d_in[5];
  const float* fval_in = (const float*)d_in[6];
  const float* w_s1_1 = (const float*)d_in[7];
  const float* b_s1_1 = (const float*)d_in[8];
  const float* w_s1_2 = (const float*)d_in[9];
  const float* b_s1_2 = (const float*)d_in[10];
  const float* w_s2_1 = (const float*)d_in[11];
  const float* b_s2_1 = (const float*)d_in[12];
  const float* w_s2_2 = (const float*)d_in[13];
  const float* b_s2_2 = (const float*)d_in[14];
  const float* w_c_1 = (const float*)d_in[15];
  const float* b_c_1 = (const float*)d_in[16];
  const float* w_c_2 = (const float*)d_in[17];
  const float* b_c_2 = (const float*)d_in[18];
  const float* attw1 = (const float*)d_in[19];
  const float* attb1 = (const float*)d_in[20];
  const float* attw2 = (const float*)d_in[21];
  const float* mlpw = (const float*)d_in[22];
  const float* mlpb = (const float*)d_in[23];

  const int n = in_sizes[0] / 128;  // 100000
  const int e = in_sizes[1];        // 1600000

  float* out = (float*)d_out;
  float* o_logp = out;
  float* o_beta = out + (size_t)n * 8;
  float* o_emb1 = out + (size_t)n * 11;
  float* o_com1 = o_emb1 + (size_t)n * 64;
  float* o_com2 = o_com1 + (size_t)n * 64;
  float* o_emb2 = o_com2 + (size_t)n * 64;
  float* o_emb = o_emb2 + (size_t)n * 64;

  // workspace layout
  float* axA = (float*)d_ws;                      // n*64 (Ax feats 0..63)
  float* axB = axA + (size_t)n * 64;              // n*64 (Ax feats 64..127)
  int* cnt = (int*)(axB + (size_t)n * 64);        // n
  int* rowptr = cnt + n;                          // n+1
  int* woff = rowptr + n + 1;                     // n
  int* part = woff + n;                           // <=256
  int* g_col = part + 256;                        // e
  float* g_val = (float*)(g_col + e);             // e

  float* hw = o_emb;  // scratch; final_fuse overwrites at the very end

  const int gemmBlocks = (n + 31) / 32;
  const int histBlocks = (e + 255) / 256;
  const int scanBlocks = (n + 1023) / 1024;
  const int spmm128Blocks = (n + 7) / 8;
  const int spmm64Blocks = (n + 15) / 16;

  auto build_csr = [&](const int* r, const int* c, const float* v) {
    hipMemsetAsync(cnt, 0, (size_t)n * sizeof(int), stream);
    hist_kernel<<<histBlocks, 256, 0, stream>>>(r, cnt, e);
    scan_partial<<<scanBlocks, 256, 0, stream>>>(cnt, part, n);
    scan_tops<<<1, 256, 0, stream>>>(part, scanBlocks);
    scan_final<<<scanBlocks, 256, 0, stream>>>(cnt, part, rowptr, woff, n, e);
    scatter_kernel<<<histBlocks, 256, 0, stream>>>(r, c, v, woff, g_col,
                                                   g_val, e);
  };

  // tail: hw = relu(Ax@W1+b1)@W2 ; dest = b2 + spmm(adj, hw)
  auto gcn_tail = [&](const float* w1, const float* bb1, const float* w2,
                      const float* bb2, float* dest) {
    fused_l1l2<<<gemmBlocks, 256, 0, stream>>>(axA, axB, w1, bb1, w2, hw, n);
    spmm_csr_64<<<spmm64Blocks, 256, 0, stream>>>(rowptr, g_col, g_val, hw,
                                                  bb2, dest, n);
  };

  // graph sadj: Ax once, then emb1 (w_s1) and com1 (w_c)
  build_csr(srow, scol_in, sval_in);
  spmm_csr_128<<<spmm128Blocks, 256, 0, stream>>>(rowptr, g_col, g_val, x,
                                                  axA, axB, n);
  gcn_tail(w_s1_1, b_s1_1, w_s1_2, b_s1_2, o_emb1);
  gcn_tail(w_c_1, b_c_1, w_c_2, b_c_2, o_com1);

  // graph fadj: Ax once, then com2 (w_c) and emb2 (w_s2)
  build_csr(frow, fcol_in, fval_in);
  spmm_csr_128<<<spmm128Blocks, 256, 0, stream>>>(rowptr, g_col, g_val, x,
                                                  axA, axB, n);
  gcn_tail(w_c_1, b_c_1, w_c_2, b_c_2, o_com2);
  gcn_tail(w_s2_1, b_s2_1, w_s2_2, b_s2_2, o_emb2);

  final_fuse<<<(int)(((long)n * 16 + 255) / 256), 256, 0, stream>>>(
      o_emb1, o_emb2, o_com1, o_com2, attw1, attb1, attw2, mlpw, mlpb, o_logp,
      o_beta, o_emb, n);
}